// Round 5
// baseline (287.433 us; speedup 1.0000x reference)
//
#include <hip/hip_runtime.h>
#include <hip/hip_bf16.h>

#define HW 36864  // 192*192

typedef __attribute__((ext_vector_type(8))) short short8;   // 8 x bf16 (4 VGPR)
typedef __attribute__((ext_vector_type(16))) float f32x16;  // 32x32 MFMA C/D

__device__ __forceinline__ unsigned short f2bf(float f) {
    unsigned u = __float_as_uint(f);
    u += 0x7fffu + ((u >> 16) & 1u);   // RNE
    return (unsigned short)(u >> 16);
}
__device__ __forceinline__ unsigned pk2(float lo, float hi) {
    unsigned r;
    asm("v_cvt_pk_bf16_f32 %0, %1, %2" : "=v"(r) : "v"(lo), "v"(hi));
    return r;
}
__device__ __forceinline__ void plswap(unsigned &a, unsigned &b) {
    asm volatile("v_permlane32_swap_b32 %0, %1" : "+v"(a), "+v"(b));
}

union FragW { unsigned u[4]; short8 s; };

// d_ws layout (bf16):
//   Qw [512][576][16]          at 0         rec = (win*576+m)*32 B
//   Kw [512][576][16]          at 9437184   same record layout (K^T)
//   Vw [512][18][64][32]       at 18874368  byte = win*73728 + mt*4096 + ch*64 + 2*ml
#define QW_OFF 0
#define KW_OFF 9437184
#define VW_OFF 18874368

// ---------------- attn1p: 4x4 window attention + fused block-2 QKV proj ------
// Block = 256 thr = 4 waves; wave = 4 adjacent windows = 64 px (2 tiles x 32).
__global__ __launch_bounds__(256) void attn1p_kernel(
    const float* __restrict__ x,
    const float* __restrict__ wq, const float* __restrict__ bq,
    const float* __restrict__ wk, const float* __restrict__ bk,
    const float* __restrict__ wv, const float* __restrict__ bv,
    const float* __restrict__ gamma, float* __restrict__ out,
    const float* __restrict__ wq2, const float* __restrict__ bq2,
    const float* __restrict__ wk2, const float* __restrict__ bk2,
    const float* __restrict__ wv2, const float* __restrict__ bv2,
    char* __restrict__ ws)
{
    __shared__ char smem[4 * 8192];

    const int tid   = threadIdx.x;
    const int wv_id = tid >> 6;
    const int lane  = tid & 63;
    const int l32   = lane & 31;
    const int h     = lane >> 5;
    char* VsW = smem + wv_id * 8192;

    const int gw0 = blockIdx.x * 16 + wv_id * 4;
    const int b_img = (blockIdx.x * 16) / 2304;   // uniform per block (2304%16==0)

    f32x16 zf;
    #pragma unroll
    for (int r = 0; r < 16; ++r) zf[r] = 0.f;

    // ---- set-1 weight/bias fragments ----------------------------------------
    FragW wqkf[4], wvf[2][4];
    {
        const float* wrow = (l32 < 16) ? (wq + l32 * 64) : (wk + (l32 - 16) * 64);
        #pragma unroll
        for (int cc = 0; cc < 4; ++cc)
            #pragma unroll
            for (int j = 0; j < 4; ++j) {
                const int c = cc * 16 + 8 * h + 2 * j;
                wqkf[cc].u[j] = pk2(wrow[c], wrow[c + 1]);
            }
        #pragma unroll
        for (int ot = 0; ot < 2; ++ot) {
            const float* wvr = wv + (size_t)(ot * 32 + l32) * 64;
            #pragma unroll
            for (int cc = 0; cc < 4; ++cc)
                #pragma unroll
                for (int j = 0; j < 4; ++j) {
                    const int c = cc * 16 + 8 * h + 2 * j;
                    wvf[ot][cc].u[j] = pk2(wvr[c], wvr[c + 1]);
                }
        }
    }
    float bqv[8], bkv[8], bvv[2][16];
    #pragma unroll
    for (int r = 0; r < 8; ++r) {
        const int c = (r & 3) + 8 * (r >> 2) + 4 * h;
        bqv[r] = bq[c];
        bkv[r] = bk[c];
    }
    #pragma unroll
    for (int ot = 0; ot < 2; ++ot)
        #pragma unroll
        for (int r = 0; r < 16; ++r)
            bvv[ot][r] = bv[ot * 32 + (r & 3) + 8 * (r >> 2) + 4 * h];

    // ---- per-tile pixel bases ------------------------------------------------
    size_t gbt[2];
    int Yt[2], Xt[2];
    #pragma unroll
    for (int t = 0; t < 2; ++t) {
        const int gwin = gw0 + 2 * t + (l32 >> 4);
        const int rem = gwin % 2304;
        const int Y = rem / 48, X = rem % 48;
        Yt[t] = Y; Xt[t] = X;
        gbt[t] = (size_t)b_img * 64 * HW + (size_t)(Y * 4 + ((l32 >> 2) & 3)) * 192
               + (X * 4 + (l32 & 3));
    }

    // ---- block-1 projection --------------------------------------------------
    FragW qf[2], kf[2];
    #pragma unroll
    for (int t = 0; t < 2; ++t) {
        const size_t gb = gbt[t];
        FragW xw[4];
        #pragma unroll
        for (int cc = 0; cc < 4; ++cc)
            #pragma unroll
            for (int j = 0; j < 4; ++j) {
                const int c = cc * 16 + 8 * h + 2 * j;
                xw[cc].u[j] = pk2(x[gb + (size_t)c * HW], x[gb + (size_t)(c + 1) * HW]);
            }

        f32x16 dqk = zf;
        #pragma unroll
        for (int cc = 0; cc < 4; ++cc)
            dqk = __builtin_amdgcn_mfma_f32_32x32x16_bf16(wqkf[cc].s, xw[cc].s, dqk, 0, 0, 0);

        {
            float q0[8];
            #pragma unroll
            for (int r = 0; r < 8; ++r) q0[r] = dqk[r] + bqv[r];
            unsigned A0 = pk2(q0[0], q0[1]), B0 = pk2(q0[2], q0[3]);
            unsigned C0 = pk2(q0[4], q0[5]), D0 = pk2(q0[6], q0[7]);
            plswap(A0, C0); plswap(B0, D0);
            qf[t].u[0] = A0; qf[t].u[1] = B0; qf[t].u[2] = C0; qf[t].u[3] = D0;
        }
        {
            float k0[8];
            #pragma unroll
            for (int r = 0; r < 8; ++r) k0[r] = dqk[8 + r] + bkv[r];
            unsigned A0 = pk2(k0[0], k0[1]), B0 = pk2(k0[2], k0[3]);
            unsigned C0 = pk2(k0[4], k0[5]), D0 = pk2(k0[6], k0[7]);
            plswap(A0, C0); plswap(B0, D0);
            kf[t].u[0] = A0; kf[t].u[1] = B0; kf[t].u[2] = C0; kf[t].u[3] = D0;
        }

        #pragma unroll
        for (int ot = 0; ot < 2; ++ot) {
            f32x16 dv = zf;
            #pragma unroll
            for (int cc = 0; cc < 4; ++cc)
                dv = __builtin_amdgcn_mfma_f32_32x32x16_bf16(wvf[ot][cc].s, xw[cc].s, dv, 0, 0, 0);
            #pragma unroll
            for (int r = 0; r < 16; ++r) {
                const int ch = ot * 32 + (r & 3) + 8 * (r >> 2) + 4 * h;
                *(unsigned short*)(VsW + ((ch * 128 + 2 * (t * 32 + l32)) ^ ((ch & 7) << 4)))
                    = f2bf(dv[r] + bvv[ot][r]);
            }
        }
    }
    __syncthreads();

    // ---- set-2 weight fragments (set-1 regs dead now) ------------------------
    FragW w2qk[4], w2v[2][4];
    {
        const float* wrow = (l32 < 16) ? (wq2 + l32 * 64) : (wk2 + (l32 - 16) * 64);
        #pragma unroll
        for (int cc = 0; cc < 4; ++cc)
            #pragma unroll
            for (int j = 0; j < 4; ++j) {
                const int c = cc * 16 + 8 * h + 2 * j;
                w2qk[cc].u[j] = pk2(wrow[c], wrow[c + 1]);
            }
        #pragma unroll
        for (int ot = 0; ot < 2; ++ot) {
            const float* wvr = wv2 + (size_t)(ot * 32 + l32) * 64;
            #pragma unroll
            for (int cc = 0; cc < 4; ++cc)
                #pragma unroll
                for (int j = 0; j < 4; ++j) {
                    const int c = cc * 16 + 8 * h + 2 * j;
                    w2v[ot][cc].u[j] = pk2(wvr[c], wvr[c + 1]);
                }
        }
    }

    char* Qw = ws + QW_OFF;
    char* Kw = ws + KW_OFF;
    char* Vw = ws + VW_OFF;

    const float g = gamma[0];
    const bool wa = (l32 < 16);

    #pragma unroll
    for (int t = 0; t < 2; ++t) {
        f32x16 sT = __builtin_amdgcn_mfma_f32_32x32x16_bf16(kf[t].s, qf[t].s, zf, 0, 0, 0);

        float e[8];
        #pragma unroll
        for (int j = 0; j < 8; ++j) e[j] = __expf(wa ? sT[j] : sT[8 + j]);
        float ls = ((e[0] + e[1]) + (e[2] + e[3])) + ((e[4] + e[5]) + (e[6] + e[7]));
        ls += __shfl_xor(ls, 32);

        unsigned A0 = pk2(e[0], e[1]), B0 = pk2(e[2], e[3]);
        unsigned C0 = pk2(e[4], e[5]), D0 = pk2(e[6], e[7]);
        plswap(A0, C0); plswap(B0, D0);
        FragW pa, pb;
        pa.u[0] = wa ? A0 : 0u; pa.u[1] = wa ? B0 : 0u;
        pa.u[2] = wa ? C0 : 0u; pa.u[3] = wa ? D0 : 0u;
        pb.u[0] = wa ? 0u : A0; pb.u[1] = wa ? 0u : B0;
        pb.u[2] = wa ? 0u : C0; pb.u[3] = wa ? 0u : D0;

        f32x16 acc0 = zf, acc1 = zf;
        #pragma unroll
        for (int wsx = 0; wsx < 2; ++wsx) {
            const short8 pfrag = wsx ? pb.s : pa.s;
            const int mbase = t * 64 + wsx * 32 + 16 * h;
            const int ch0 = l32, ch1 = 32 + l32;
            const short8 v0 = *(const short8*)(VsW + ((ch0 * 128 + mbase) ^ ((ch0 & 7) << 4)));
            const short8 v1 = *(const short8*)(VsW + ((ch1 * 128 + mbase) ^ ((ch1 & 7) << 4)));
            acc0 = __builtin_amdgcn_mfma_f32_32x32x16_bf16(v0, pfrag, acc0, 0, 0, 0);
            acc1 = __builtin_amdgcn_mfma_f32_32x32x16_bf16(v1, pfrag, acc1, 0, 0, 0);
        }

        const float inv = 1.f / ls;
        const size_t gb = gbt[t];
        float o0[16], o1[16];
        #pragma unroll
        for (int r = 0; r < 16; ++r) {
            const int cA = (r & 3) + 8 * (r >> 2) + 4 * h;
            const int cB = 32 + cA;
            const size_t iA = gb + (size_t)cA * HW;
            const size_t iB = gb + (size_t)cB * HW;
            o0[r] = fmaf(g, acc0[r] * inv, x[iA]);
            o1[r] = fmaf(g, acc1[r] * inv, x[iB]);
            out[iA] = o0[r];
            out[iB] = o1[r];
        }

        // ---- fused block-2 projection for this tile's pixels -----------------
        // out D-frag -> X2 B-frags (verified pk2+plswap builder)
        FragW x2[4];
        #pragma unroll
        for (int cc = 0; cc < 4; ++cc) {
            const float* src = (cc < 2) ? o0 : o1;
            const int base = (cc & 1) * 8;
            unsigned A1 = pk2(src[base + 0], src[base + 1]);
            unsigned B1 = pk2(src[base + 2], src[base + 3]);
            unsigned C1 = pk2(src[base + 4], src[base + 5]);
            unsigned D1 = pk2(src[base + 6], src[base + 7]);
            plswap(A1, C1); plswap(B1, D1);
            x2[cc].u[0] = A1; x2[cc].u[1] = B1; x2[cc].u[2] = C1; x2[cc].u[3] = D1;
        }

        // chess coords for this lane's pixel
        const int yy  = Yt[t] * 4 + ((l32 >> 2) & 3);
        const int xx2 = Xt[t] * 4 + (l32 & 3);
        const int win2 = b_img * 64 + (xx2 & 7) * 8 + (yy & 7);
        const int m2   = (yy >> 3) * 24 + (xx2 >> 3);
        const size_t rec2 = (size_t)(win2 * 576 + m2) * 32;
        const size_t vb2  = (size_t)win2 * 73728 + (size_t)(m2 >> 5) * 4096 + 2 * (m2 & 31);

        // Q2/K2 (bias via C-init)
        f32x16 ci;
        #pragma unroll
        for (int r = 0; r < 8; ++r)  ci[r] = bq2[(r & 3) + 8 * (r >> 2) + 4 * h];
        #pragma unroll
        for (int r = 8; r < 16; ++r) ci[r] = bk2[(r & 3) + 8 * ((r >> 2) & 1) + 4 * h];
        f32x16 dqk2 = ci;
        #pragma unroll
        for (int cc = 0; cc < 4; ++cc)
            dqk2 = __builtin_amdgcn_mfma_f32_32x32x16_bf16(w2qk[cc].s, x2[cc].s, dqk2, 0, 0, 0);

        #pragma unroll
        for (int k = 0; k < 2; ++k) {
            unsigned u0 = pk2(dqk2[4 * k], dqk2[4 * k + 1]);
            unsigned u1 = pk2(dqk2[4 * k + 2], dqk2[4 * k + 3]);
            *(unsigned*)(Qw + rec2 + 8 * h + 16 * k) = u0;
            *(unsigned*)(Qw + rec2 + 8 * h + 16 * k + 4) = u1;
            const int r8 = 8 + 4 * k;
            unsigned w0 = pk2(dqk2[r8], dqk2[r8 + 1]);
            unsigned w1 = pk2(dqk2[r8 + 2], dqk2[r8 + 3]);
            *(unsigned*)(Kw + rec2 + 8 * h + 16 * k) = w0;
            *(unsigned*)(Kw + rec2 + 8 * h + 16 * k + 4) = w1;
        }

        // V2
        #pragma unroll
        for (int ot = 0; ot < 2; ++ot) {
            f32x16 civ;
            #pragma unroll
            for (int r = 0; r < 16; ++r)
                civ[r] = bv2[ot * 32 + (r & 3) + 8 * (r >> 2) + 4 * h];
            f32x16 dv2 = civ;
            #pragma unroll
            for (int cc = 0; cc < 4; ++cc)
                dv2 = __builtin_amdgcn_mfma_f32_32x32x16_bf16(w2v[ot][cc].s, x2[cc].s, dv2, 0, 0, 0);
            #pragma unroll
            for (int r = 0; r < 16; ++r) {
                const int ch = ot * 32 + (r & 3) + 8 * (r >> 2) + 4 * h;
                *(unsigned short*)(Vw + vb2 + ch * 64) = f2bf(dv2[r]);
            }
        }
    }
}

// ---------------- attn2c: 8x8 chess attention consumer ----------------------
// One block per window, 576 threads = 9 waves. V tile-staged (double-buffered
// 2 x 5120 B LDS, 80 B row stride); K prefetch depth 2; Q in registers.
__global__ __launch_bounds__(576) void attn2c_kernel(
    float* io, const char* __restrict__ ws, const float* __restrict__ gamma)
{
    __shared__ char smem[2 * 5120];

    const int wid = blockIdx.x;
    const int b  = wid >> 6;
    const int a  = wid & 7;
    const int c0 = (wid >> 3) & 7;

    const int tid = threadIdx.x;
    const int wv_id = tid >> 6;
    const int l32 = tid & 31;
    const int h   = (tid >> 5) & 1;
    const int n0  = wv_id * 64;
    const size_t bbase = (size_t)b * 64 * HW;

    const char* Qw = ws + QW_OFF + (size_t)wid * 18432;
    const char* Kw = ws + KW_OFF + (size_t)wid * 18432;
    const char* Vw = ws + VW_OFF + (size_t)wid * 73728;

    // stage V tile 0 (threads 0..255: 16B each, coalesced)
    const bool st = (tid < 256);
    const int sch = tid >> 2, ssl = tid & 3;
    short8 stg;
    if (st) stg = *(const short8*)(Vw + tid * 16);

    // Q fragments (coalesced 16B/lane)
    const short8 qf0 = *(const short8*)(Qw + (n0 + l32) * 32 + 16 * h);
    const short8 qf1 = *(const short8*)(Qw + (n0 + 32 + l32) * 32 + 16 * h);

    // K prefetch depth 2
    short8 kf0 = *(const short8*)(Kw + l32 * 32 + 16 * h);
    short8 kf1 = *(const short8*)(Kw + (32 + l32) * 32 + 16 * h);

    if (st) *(short8*)(smem + sch * 80 + ssl * 16) = stg;

    f32x16 zf;
    #pragma unroll
    for (int r = 0; r < 16; ++r) zf[r] = 0.f;

    __syncthreads();

    f32x16 accA = zf, accB = zf, accC = zf, accD = zf;
    float ls0 = 0.f, ls1 = 0.f;
    const int chA = l32, chB = 32 + l32;

    #pragma unroll 1
    for (int mt = 0; mt < 18; ++mt) {
        const int cur = mt & 1;
        char* buf = smem + cur * 5120;

        // issue next V tile + next K early
        if (mt < 17 && st) stg = *(const short8*)(Vw + (mt + 1) * 4096 + tid * 16);
        short8 kf2 = kf0;
        if (mt < 16) kf2 = *(const short8*)(Kw + ((mt + 2) * 32 + l32) * 32 + 16 * h);

        f32x16 s0 = __builtin_amdgcn_mfma_f32_32x32x16_bf16(kf0, qf0, zf, 0, 0, 0);
        f32x16 s1 = __builtin_amdgcn_mfma_f32_32x32x16_bf16(kf0, qf1, zf, 0, 0, 0);

        const short8 vA0 = *(const short8*)(buf + chA * 80 + 16 * h);
        const short8 vA1 = *(const short8*)(buf + chA * 80 + 32 + 16 * h);
        const short8 vB0 = *(const short8*)(buf + chB * 80 + 16 * h);
        const short8 vB1 = *(const short8*)(buf + chB * 80 + 32 + 16 * h);

        #pragma unroll
        for (int r = 0; r < 16; ++r) s0[r] = __expf(s0[r]);
        #pragma unroll
        for (int r = 0; r < 16; ++r) s1[r] = __expf(s1[r]);
        ls0 += ((s0[0]+s0[1])+(s0[2]+s0[3])) + ((s0[4]+s0[5])+(s0[6]+s0[7]))
             + ((s0[8]+s0[9])+(s0[10]+s0[11])) + ((s0[12]+s0[13])+(s0[14]+s0[15]));
        ls1 += ((s1[0]+s1[1])+(s1[2]+s1[3])) + ((s1[4]+s1[5])+(s1[6]+s1[7]))
             + ((s1[8]+s1[9])+(s1[10]+s1[11])) + ((s1[12]+s1[13])+(s1[14]+s1[15]));

        FragW pf00, pf01, pf10, pf11;
        {
            unsigned A0 = pk2(s0[0], s0[1]), B0 = pk2(s0[2], s0[3]);
            unsigned C0 = pk2(s0[4], s0[5]), D0 = pk2(s0[6], s0[7]);
            plswap(A0, C0); plswap(B0, D0);
            pf00.u[0] = A0; pf00.u[1] = B0; pf00.u[2] = C0; pf00.u[3] = D0;
            unsigned E0 = pk2(s0[8], s0[9]),  F0 = pk2(s0[10], s0[11]);
            unsigned G0 = pk2(s0[12], s0[13]), H0 = pk2(s0[14], s0[15]);
            plswap(E0, G0); plswap(F0, H0);
            pf01.u[0] = E0; pf01.u[1] = F0; pf01.u[2] = G0; pf01.u[3] = H0;
            unsigned A1 = pk2(s1[0], s1[1]), B1 = pk2(s1[2], s1[3]);
            unsigned C1 = pk2(s1[4], s1[5]), D1 = pk2(s1[6], s1[7]);
            plswap(A1, C1); plswap(B1, D1);
            pf10.u[0] = A1; pf10.u[1] = B1; pf10.u[2] = C1; pf10.u[3] = D1;
            unsigned E1 = pk2(s1[8], s1[9]),  F1 = pk2(s1[10], s1[11]);
            unsigned G1 = pk2(s1[12], s1[13]), H1 = pk2(s1[14], s1[15]);
            plswap(E1, G1); plswap(F1, H1);
            pf11.u[0] = E1; pf11.u[1] = F1; pf11.u[2] = G1; pf11.u[3] = H1;
        }

        accA = __builtin_amdgcn_mfma_f32_32x32x16_bf16(vA0, pf00.s, accA, 0, 0, 0);
        accA = __builtin_amdgcn_mfma_f32_32x32x16_bf16(vA1, pf01.s, accA, 0, 0, 0);
        accB = __builtin_amdgcn_mfma_f32_32x32x16_bf16(vB0, pf00.s, accB, 0, 0, 0);
        accB = __builtin_amdgcn_mfma_f32_32x32x16_bf16(vB1, pf01.s, accB, 0, 0, 0);
        accC = __builtin_amdgcn_mfma_f32_32x32x16_bf16(vA0, pf10.s, accC, 0, 0, 0);
        accC = __builtin_amdgcn_mfma_f32_32x32x16_bf16(vA1, pf11.s, accC, 0, 0, 0);
        accD = __builtin_amdgcn_mfma_f32_32x32x16_bf16(vB0, pf10.s, accD, 0, 0, 0);
        accD = __builtin_amdgcn_mfma_f32_32x32x16_bf16(vB1, pf11.s, accD, 0, 0, 0);

        // write next tile into the other buffer, then sync
        if (mt < 17 && st) *(short8*)(smem + (cur ^ 1) * 5120 + sch * 80 + ssl * 16) = stg;
        __syncthreads();

        kf0 = kf1; kf1 = kf2;
    }

    ls0 += __shfl_xor(ls0, 32);
    ls1 += __shfl_xor(ls1, 32);
    const float g = gamma[0];
    const float inv0 = 1.f / ls0, inv1 = 1.f / ls1;

    const int pn0 = n0 + l32, pn1 = n0 + 32 + l32;
    const int i0 = pn0 / 24, j0 = pn0 - i0 * 24;
    const int i1 = pn1 / 24, j1 = pn1 - i1 * 24;
    const size_t gb0 = bbase + (size_t)(a + 8 * i0) * 192 + (c0 + 8 * j0);
    const size_t gb1 = bbase + (size_t)(a + 8 * i1) * 192 + (c0 + 8 * j1);

    #pragma unroll
    for (int r = 0; r < 16; ++r) {
        const int cA = (r & 3) + 8 * (r >> 2) + 4 * h;
        const int cB = 32 + cA;
        const size_t iA0 = gb0 + (size_t)cA * HW;
        const size_t iB0 = gb0 + (size_t)cB * HW;
        const size_t iA1 = gb1 + (size_t)cA * HW;
        const size_t iB1 = gb1 + (size_t)cB * HW;
        io[iA0] = fmaf(g, accA[r] * inv0, io[iA0]);
        io[iB0] = fmaf(g, accB[r] * inv0, io[iB0]);
        io[iA1] = fmaf(g, accC[r] * inv1, io[iA1]);
        io[iB1] = fmaf(g, accD[r] * inv1, io[iB1]);
    }
}

extern "C" void kernel_launch(void* const* d_in, const int* in_sizes, int n_in,
                              void* d_out, int out_size, void* d_ws, size_t ws_size,
                              hipStream_t stream)
{
    const float* x   = (const float*)d_in[0];
    const float* wq1 = (const float*)d_in[1];
    const float* bq1 = (const float*)d_in[2];
    const float* wk1 = (const float*)d_in[3];
    const float* bk1 = (const float*)d_in[4];
    const float* wv1 = (const float*)d_in[5];
    const float* bv1 = (const float*)d_in[6];
    const float* wq2 = (const float*)d_in[7];
    const float* bq2 = (const float*)d_in[8];
    const float* wk2 = (const float*)d_in[9];
    const float* bk2 = (const float*)d_in[10];
    const float* wv2 = (const float*)d_in[11];
    const float* bv2 = (const float*)d_in[12];
    const float* g1  = (const float*)d_in[13];
    const float* g2  = (const float*)d_in[14];
    float* out = (float*)d_out;
    char* ws = (char*)d_ws;

    attn1p_kernel<<<dim3(1152), dim3(256), 0, stream>>>(
        x, wq1, bq1, wk1, bk1, wv1, bv1, g1, out,
        wq2, bq2, wk2, bk2, wv2, bv2, ws);

    attn2c_kernel<<<dim3(512), dim3(576), 0, stream>>>(
        out, ws, g2);
}

// Round 6
// 229.427 us; speedup vs baseline: 1.2528x; 1.2528x over previous
//
#include <hip/hip_runtime.h>
#include <hip/hip_bf16.h>

#define HW 36864  // 192*192

typedef __attribute__((ext_vector_type(8))) short short8;   // 8 x bf16 (4 VGPR)
typedef __attribute__((ext_vector_type(16))) float f32x16;  // 32x32 MFMA C/D

__device__ __forceinline__ unsigned short f2bf(float f) {
    unsigned u = __float_as_uint(f);
    u += 0x7fffu + ((u >> 16) & 1u);   // RNE
    return (unsigned short)(u >> 16);
}
__device__ __forceinline__ unsigned pk2(float lo, float hi) {
    unsigned r;
    asm("v_cvt_pk_bf16_f32 %0, %1, %2" : "=v"(r) : "v"(lo), "v"(hi));
    return r;
}
__device__ __forceinline__ void plswap(unsigned &a, unsigned &b) {
    asm volatile("v_permlane32_swap_b32 %0, %1" : "+v"(a), "+v"(b));
}

union FragW { unsigned u[4]; short8 s; };

// d_ws layout (bf16):
//   Qw [512][576][16]      at 0         rec = (win*576+m)*32 B
//   Kw [512][576][16]      at 9437184   same record layout (K^T)
//   Vw [512][18][64][32]   at 18874368  byte = win*73728 + mt*4096 + ch*64 + 2*ml
#define QW_OFF 0
#define KW_OFF 9437184
#define VW_OFF 18874368

// ---------------- Block 1: 4x4 window attention, MFMA ------------------------
__global__ __launch_bounds__(256) void attn1_mfma(
    const float* __restrict__ x,
    const float* __restrict__ wq, const float* __restrict__ bq,
    const float* __restrict__ wk, const float* __restrict__ bk,
    const float* __restrict__ wv, const float* __restrict__ bv,
    const float* __restrict__ gamma, float* __restrict__ out)
{
    __shared__ char smem[4 * 8192];

    const int tid   = threadIdx.x;
    const int wv_id = tid >> 6;
    const int lane  = tid & 63;
    const int l32   = lane & 31;
    const int h     = lane >> 5;
    char* VsW = smem + wv_id * 8192;

    const int gw0 = blockIdx.x * 16 + wv_id * 4;

    f32x16 zf;
    #pragma unroll
    for (int r = 0; r < 16; ++r) zf[r] = 0.f;

    // ---- weight/bias fragments (float4 loads) -------------------------------
    FragW wqkf[4], wvf[2][4];
    {
        const float4* wrow4 = (const float4*)((l32 < 16) ? (wq + l32 * 64)
                                                         : (wk + (l32 - 16) * 64));
        #pragma unroll
        for (int cc = 0; cc < 4; ++cc) {
            const float4 a = wrow4[cc * 4 + 2 * h];
            const float4 b = wrow4[cc * 4 + 2 * h + 1];
            wqkf[cc].u[0] = pk2(a.x, a.y); wqkf[cc].u[1] = pk2(a.z, a.w);
            wqkf[cc].u[2] = pk2(b.x, b.y); wqkf[cc].u[3] = pk2(b.z, b.w);
        }
        #pragma unroll
        for (int ot = 0; ot < 2; ++ot) {
            const float4* wvr4 = (const float4*)(wv + (size_t)(ot * 32 + l32) * 64);
            #pragma unroll
            for (int cc = 0; cc < 4; ++cc) {
                const float4 a = wvr4[cc * 4 + 2 * h];
                const float4 b = wvr4[cc * 4 + 2 * h + 1];
                wvf[ot][cc].u[0] = pk2(a.x, a.y); wvf[ot][cc].u[1] = pk2(a.z, a.w);
                wvf[ot][cc].u[2] = pk2(b.x, b.y); wvf[ot][cc].u[3] = pk2(b.z, b.w);
            }
        }
    }
    float bqv[8], bkv[8], bvv[2][16];
    #pragma unroll
    for (int r = 0; r < 8; ++r) {
        const int c = (r & 3) + 8 * (r >> 2) + 4 * h;
        bqv[r] = bq[c];
        bkv[r] = bk[c];
    }
    #pragma unroll
    for (int ot = 0; ot < 2; ++ot)
        #pragma unroll
        for (int r = 0; r < 16; ++r)
            bvv[ot][r] = bv[ot * 32 + (r & 3) + 8 * (r >> 2) + 4 * h];

    size_t gbt[2];
    #pragma unroll
    for (int t = 0; t < 2; ++t) {
        const int gwin = gw0 + 2 * t + (l32 >> 4);
        const int b = gwin / 2304;
        const int rem = gwin % 2304;
        const int Y = rem / 48, X = rem % 48;
        gbt[t] = (size_t)b * 64 * HW + (size_t)(Y * 4 + ((l32 >> 2) & 3)) * 192
               + (X * 4 + (l32 & 3));
    }

    FragW qf[2], kf[2];
    #pragma unroll
    for (int t = 0; t < 2; ++t) {
        const size_t gb = gbt[t];
        FragW xw[4];
        #pragma unroll
        for (int cc = 0; cc < 4; ++cc)
            #pragma unroll
            for (int j = 0; j < 4; ++j) {
                const int c = cc * 16 + 8 * h + 2 * j;
                xw[cc].u[j] = pk2(x[gb + (size_t)c * HW], x[gb + (size_t)(c + 1) * HW]);
            }

        f32x16 dqk = zf;
        #pragma unroll
        for (int cc = 0; cc < 4; ++cc)
            dqk = __builtin_amdgcn_mfma_f32_32x32x16_bf16(wqkf[cc].s, xw[cc].s, dqk, 0, 0, 0);

        {
            float q0[8];
            #pragma unroll
            for (int r = 0; r < 8; ++r) q0[r] = dqk[r] + bqv[r];
            unsigned A0 = pk2(q0[0], q0[1]), B0 = pk2(q0[2], q0[3]);
            unsigned C0 = pk2(q0[4], q0[5]), D0 = pk2(q0[6], q0[7]);
            plswap(A0, C0); plswap(B0, D0);
            qf[t].u[0] = A0; qf[t].u[1] = B0; qf[t].u[2] = C0; qf[t].u[3] = D0;
        }
        {
            float k0[8];
            #pragma unroll
            for (int r = 0; r < 8; ++r) k0[r] = dqk[8 + r] + bkv[r];
            unsigned A0 = pk2(k0[0], k0[1]), B0 = pk2(k0[2], k0[3]);
            unsigned C0 = pk2(k0[4], k0[5]), D0 = pk2(k0[6], k0[7]);
            plswap(A0, C0); plswap(B0, D0);
            kf[t].u[0] = A0; kf[t].u[1] = B0; kf[t].u[2] = C0; kf[t].u[3] = D0;
        }

        #pragma unroll
        for (int ot = 0; ot < 2; ++ot) {
            f32x16 dv = zf;
            #pragma unroll
            for (int cc = 0; cc < 4; ++cc)
                dv = __builtin_amdgcn_mfma_f32_32x32x16_bf16(wvf[ot][cc].s, xw[cc].s, dv, 0, 0, 0);
            #pragma unroll
            for (int r = 0; r < 16; ++r) {
                const int ch = ot * 32 + (r & 3) + 8 * (r >> 2) + 4 * h;
                *(unsigned short*)(VsW + ((ch * 128 + 2 * (t * 32 + l32)) ^ ((ch & 7) << 4)))
                    = f2bf(dv[r] + bvv[ot][r]);
            }
        }
    }
    __syncthreads();

    const float g = gamma[0];
    const bool wa = (l32 < 16);

    #pragma unroll
    for (int t = 0; t < 2; ++t) {
        f32x16 sT = __builtin_amdgcn_mfma_f32_32x32x16_bf16(kf[t].s, qf[t].s, zf, 0, 0, 0);

        float e[8];
        #pragma unroll
        for (int j = 0; j < 8; ++j) e[j] = __expf(wa ? sT[j] : sT[8 + j]);
        float ls = ((e[0] + e[1]) + (e[2] + e[3])) + ((e[4] + e[5]) + (e[6] + e[7]));
        ls += __shfl_xor(ls, 32);

        unsigned A0 = pk2(e[0], e[1]), B0 = pk2(e[2], e[3]);
        unsigned C0 = pk2(e[4], e[5]), D0 = pk2(e[6], e[7]);
        plswap(A0, C0); plswap(B0, D0);
        FragW pa, pb;
        pa.u[0] = wa ? A0 : 0u; pa.u[1] = wa ? B0 : 0u;
        pa.u[2] = wa ? C0 : 0u; pa.u[3] = wa ? D0 : 0u;
        pb.u[0] = wa ? 0u : A0; pb.u[1] = wa ? 0u : B0;
        pb.u[2] = wa ? 0u : C0; pb.u[3] = wa ? 0u : D0;

        f32x16 acc0 = zf, acc1 = zf;
        #pragma unroll
        for (int wsx = 0; wsx < 2; ++wsx) {
            const short8 pfrag = wsx ? pb.s : pa.s;
            const int mbase = t * 64 + wsx * 32 + 16 * h;
            const int ch0 = l32, ch1 = 32 + l32;
            const short8 v0 = *(const short8*)(VsW + ((ch0 * 128 + mbase) ^ ((ch0 & 7) << 4)));
            const short8 v1 = *(const short8*)(VsW + ((ch1 * 128 + mbase) ^ ((ch1 & 7) << 4)));
            acc0 = __builtin_amdgcn_mfma_f32_32x32x16_bf16(v0, pfrag, acc0, 0, 0, 0);
            acc1 = __builtin_amdgcn_mfma_f32_32x32x16_bf16(v1, pfrag, acc1, 0, 0, 0);
        }

        const float inv = 1.f / ls;
        const size_t gb = gbt[t];
        #pragma unroll
        for (int r = 0; r < 16; ++r) {
            const int cA = (r & 3) + 8 * (r >> 2) + 4 * h;
            const int cB = 32 + cA;
            const size_t iA = gb + (size_t)cA * HW;
            const size_t iB = gb + (size_t)cB * HW;
            out[iA] = fmaf(g, acc0[r] * inv, x[iA]);
            out[iB] = fmaf(g, acc1[r] * inv, x[iB]);
        }
    }
}

// ---------------- proj2w: block-2 QKV projection, window-gathered ------------
// One block per chess window (same wid decode as attn2c). 576 thr = 9 waves;
// wave w owns m-tiles {2w, 2w+1}, lane = m within tile. Reads of io are
// stride-8 scattered (L2-absorbed); ALL writes window-local and coalesced.
__global__ __launch_bounds__(576) void proj2w_kernel(
    const float* __restrict__ io,
    const float* __restrict__ wq, const float* __restrict__ bq,
    const float* __restrict__ wk, const float* __restrict__ bk,
    const float* __restrict__ wv, const float* __restrict__ bv,
    char* __restrict__ ws)
{
    const int wid = blockIdx.x;
    const int b  = wid >> 6;
    const int a  = wid & 7;
    const int c0 = (wid >> 3) & 7;

    const int tid = threadIdx.x;
    const int w   = tid >> 6;
    const int l32 = tid & 31;
    const int h   = (tid >> 5) & 1;

    f32x16 zf;
    #pragma unroll
    for (int r = 0; r < 16; ++r) zf[r] = 0.f;

    // ---- weight/bias fragments (float4 loads) -------------------------------
    FragW wqkf[4], wvf[2][4];
    {
        const float4* wrow4 = (const float4*)((l32 < 16) ? (wq + l32 * 64)
                                                         : (wk + (l32 - 16) * 64));
        #pragma unroll
        for (int cc = 0; cc < 4; ++cc) {
            const float4 a4 = wrow4[cc * 4 + 2 * h];
            const float4 b4 = wrow4[cc * 4 + 2 * h + 1];
            wqkf[cc].u[0] = pk2(a4.x, a4.y); wqkf[cc].u[1] = pk2(a4.z, a4.w);
            wqkf[cc].u[2] = pk2(b4.x, b4.y); wqkf[cc].u[3] = pk2(b4.z, b4.w);
        }
        #pragma unroll
        for (int ot = 0; ot < 2; ++ot) {
            const float4* wvr4 = (const float4*)(wv + (size_t)(ot * 32 + l32) * 64);
            #pragma unroll
            for (int cc = 0; cc < 4; ++cc) {
                const float4 a4 = wvr4[cc * 4 + 2 * h];
                const float4 b4 = wvr4[cc * 4 + 2 * h + 1];
                wvf[ot][cc].u[0] = pk2(a4.x, a4.y); wvf[ot][cc].u[1] = pk2(a4.z, a4.w);
                wvf[ot][cc].u[2] = pk2(b4.x, b4.y); wvf[ot][cc].u[3] = pk2(b4.z, b4.w);
            }
        }
    }
    float bias_qk[16], bvv[2][16];
    #pragma unroll
    for (int r = 0; r < 8; ++r) {
        const int c = (r & 3) + 8 * (r >> 2) + 4 * h;
        bias_qk[r] = bq[c];
        bias_qk[8 + r] = bk[c];
    }
    #pragma unroll
    for (int ot = 0; ot < 2; ++ot)
        #pragma unroll
        for (int r = 0; r < 16; ++r)
            bvv[ot][r] = bv[ot * 32 + (r & 3) + 8 * (r >> 2) + 4 * h];

    char* Qw = ws + QW_OFF + (size_t)wid * 18432;
    char* Kw = ws + KW_OFF + (size_t)wid * 18432;
    char* Vw = ws + VW_OFF + (size_t)wid * 73728;

    #pragma unroll
    for (int t = 0; t < 2; ++t) {
        const int m = w * 64 + t * 32 + l32;
        const int i = m / 24, j = m - i * 24;
        const size_t gb = (size_t)b * 64 * HW + (size_t)(a + 8 * i) * 192 + (c0 + 8 * j);

        FragW xw[4];
        #pragma unroll
        for (int cc = 0; cc < 4; ++cc)
            #pragma unroll
            for (int jj = 0; jj < 4; ++jj) {
                const int c = cc * 16 + 8 * h + 2 * jj;
                xw[cc].u[jj] = pk2(io[gb + (size_t)c * HW], io[gb + (size_t)(c + 1) * HW]);
            }

        f32x16 dqk = zf;
        #pragma unroll
        for (int cc = 0; cc < 4; ++cc)
            dqk = __builtin_amdgcn_mfma_f32_32x32x16_bf16(wqkf[cc].s, xw[cc].s, dqk, 0, 0, 0);

        const size_t rec = (size_t)m * 32;
        #pragma unroll
        for (int k = 0; k < 2; ++k) {
            unsigned u0 = pk2(dqk[4 * k] + bias_qk[4 * k], dqk[4 * k + 1] + bias_qk[4 * k + 1]);
            unsigned u1 = pk2(dqk[4 * k + 2] + bias_qk[4 * k + 2], dqk[4 * k + 3] + bias_qk[4 * k + 3]);
            *(unsigned*)(Qw + rec + 8 * h + 16 * k) = u0;
            *(unsigned*)(Qw + rec + 8 * h + 16 * k + 4) = u1;
            const int r8 = 8 + 4 * k;
            unsigned w0 = pk2(dqk[r8] + bias_qk[r8], dqk[r8 + 1] + bias_qk[r8 + 1]);
            unsigned w1 = pk2(dqk[r8 + 2] + bias_qk[r8 + 2], dqk[r8 + 3] + bias_qk[r8 + 3]);
            *(unsigned*)(Kw + rec + 8 * h + 16 * k) = w0;
            *(unsigned*)(Kw + rec + 8 * h + 16 * k + 4) = w1;
        }

        const size_t vb = (size_t)(2 * w + t) * 4096 + 2 * l32;
        #pragma unroll
        for (int ot = 0; ot < 2; ++ot) {
            f32x16 dv = zf;
            #pragma unroll
            for (int cc = 0; cc < 4; ++cc)
                dv = __builtin_amdgcn_mfma_f32_32x32x16_bf16(wvf[ot][cc].s, xw[cc].s, dv, 0, 0, 0);
            #pragma unroll
            for (int r = 0; r < 16; ++r) {
                const int ch = ot * 32 + (r & 3) + 8 * (r >> 2) + 4 * h;
                *(unsigned short*)(Vw + vb + ch * 64) = f2bf(dv[r] + bvv[ot][r]);
            }
        }
    }
}

// ---------------- attn2c: 8x8 chess attention consumer (round-5) -------------
__global__ __launch_bounds__(576) void attn2c_kernel(
    float* io, const char* __restrict__ ws, const float* __restrict__ gamma)
{
    __shared__ char smem[2 * 5120];

    const int wid = blockIdx.x;
    const int b  = wid >> 6;
    const int a  = wid & 7;
    const int c0 = (wid >> 3) & 7;

    const int tid = threadIdx.x;
    const int wv_id = tid >> 6;
    const int l32 = tid & 31;
    const int h   = (tid >> 5) & 1;
    const int n0  = wv_id * 64;
    const size_t bbase = (size_t)b * 64 * HW;

    const char* Qw = ws + QW_OFF + (size_t)wid * 18432;
    const char* Kw = ws + KW_OFF + (size_t)wid * 18432;
    const char* Vw = ws + VW_OFF + (size_t)wid * 73728;

    const bool st = (tid < 256);
    const int sch = tid >> 2, ssl = tid & 3;
    short8 stg;
    if (st) stg = *(const short8*)(Vw + tid * 16);

    const short8 qf0 = *(const short8*)(Qw + (n0 + l32) * 32 + 16 * h);
    const short8 qf1 = *(const short8*)(Qw + (n0 + 32 + l32) * 32 + 16 * h);

    short8 kf0 = *(const short8*)(Kw + l32 * 32 + 16 * h);
    short8 kf1 = *(const short8*)(Kw + (32 + l32) * 32 + 16 * h);

    if (st) *(short8*)(smem + sch * 80 + ssl * 16) = stg;

    f32x16 zf;
    #pragma unroll
    for (int r = 0; r < 16; ++r) zf[r] = 0.f;

    __syncthreads();

    f32x16 accA = zf, accB = zf, accC = zf, accD = zf;
    float ls0 = 0.f, ls1 = 0.f;
    const int chA = l32, chB = 32 + l32;

    #pragma unroll 1
    for (int mt = 0; mt < 18; ++mt) {
        const int cur = mt & 1;
        char* buf = smem + cur * 5120;

        if (mt < 17 && st) stg = *(const short8*)(Vw + (mt + 1) * 4096 + tid * 16);
        short8 kf2 = kf0;
        if (mt < 16) kf2 = *(const short8*)(Kw + ((mt + 2) * 32 + l32) * 32 + 16 * h);

        f32x16 s0 = __builtin_amdgcn_mfma_f32_32x32x16_bf16(kf0, qf0, zf, 0, 0, 0);
        f32x16 s1 = __builtin_amdgcn_mfma_f32_32x32x16_bf16(kf0, qf1, zf, 0, 0, 0);

        const short8 vA0 = *(const short8*)(buf + chA * 80 + 16 * h);
        const short8 vA1 = *(const short8*)(buf + chA * 80 + 32 + 16 * h);
        const short8 vB0 = *(const short8*)(buf + chB * 80 + 16 * h);
        const short8 vB1 = *(const short8*)(buf + chB * 80 + 32 + 16 * h);

        #pragma unroll
        for (int r = 0; r < 16; ++r) s0[r] = __expf(s0[r]);
        #pragma unroll
        for (int r = 0; r < 16; ++r) s1[r] = __expf(s1[r]);
        ls0 += ((s0[0]+s0[1])+(s0[2]+s0[3])) + ((s0[4]+s0[5])+(s0[6]+s0[7]))
             + ((s0[8]+s0[9])+(s0[10]+s0[11])) + ((s0[12]+s0[13])+(s0[14]+s0[15]));
        ls1 += ((s1[0]+s1[1])+(s1[2]+s1[3])) + ((s1[4]+s1[5])+(s1[6]+s1[7]))
             + ((s1[8]+s1[9])+(s1[10]+s1[11])) + ((s1[12]+s1[13])+(s1[14]+s1[15]));

        FragW pf00, pf01, pf10, pf11;
        {
            unsigned A0 = pk2(s0[0], s0[1]), B0 = pk2(s0[2], s0[3]);
            unsigned C0 = pk2(s0[4], s0[5]), D0 = pk2(s0[6], s0[7]);
            plswap(A0, C0); plswap(B0, D0);
            pf00.u[0] = A0; pf00.u[1] = B0; pf00.u[2] = C0; pf00.u[3] = D0;
            unsigned E0 = pk2(s0[8], s0[9]),  F0 = pk2(s0[10], s0[11]);
            unsigned G0 = pk2(s0[12], s0[13]), H0 = pk2(s0[14], s0[15]);
            plswap(E0, G0); plswap(F0, H0);
            pf01.u[0] = E0; pf01.u[1] = F0; pf01.u[2] = G0; pf01.u[3] = H0;
            unsigned A1 = pk2(s1[0], s1[1]), B1 = pk2(s1[2], s1[3]);
            unsigned C1 = pk2(s1[4], s1[5]), D1 = pk2(s1[6], s1[7]);
            plswap(A1, C1); plswap(B1, D1);
            pf10.u[0] = A1; pf10.u[1] = B1; pf10.u[2] = C1; pf10.u[3] = D1;
            unsigned E1 = pk2(s1[8], s1[9]),  F1 = pk2(s1[10], s1[11]);
            unsigned G1 = pk2(s1[12], s1[13]), H1 = pk2(s1[14], s1[15]);
            plswap(E1, G1); plswap(F1, H1);
            pf11.u[0] = E1; pf11.u[1] = F1; pf11.u[2] = G1; pf11.u[3] = H1;
        }

        accA = __builtin_amdgcn_mfma_f32_32x32x16_bf16(vA0, pf00.s, accA, 0, 0, 0);
        accA = __builtin_amdgcn_mfma_f32_32x32x16_bf16(vA1, pf01.s, accA, 0, 0, 0);
        accB = __builtin_amdgcn_mfma_f32_32x32x16_bf16(vB0, pf00.s, accB, 0, 0, 0);
        accB = __builtin_amdgcn_mfma_f32_32x32x16_bf16(vB1, pf01.s, accB, 0, 0, 0);
        accC = __builtin_amdgcn_mfma_f32_32x32x16_bf16(vA0, pf10.s, accC, 0, 0, 0);
        accC = __builtin_amdgcn_mfma_f32_32x32x16_bf16(vA1, pf11.s, accC, 0, 0, 0);
        accD = __builtin_amdgcn_mfma_f32_32x32x16_bf16(vB0, pf10.s, accD, 0, 0, 0);
        accD = __builtin_amdgcn_mfma_f32_32x32x16_bf16(vB1, pf11.s, accD, 0, 0, 0);

        if (mt < 17 && st) *(short8*)(smem + (cur ^ 1) * 5120 + sch * 80 + ssl * 16) = stg;
        __syncthreads();

        kf0 = kf1; kf1 = kf2;
    }

    ls0 += __shfl_xor(ls0, 32);
    ls1 += __shfl_xor(ls1, 32);
    const float g = gamma[0];
    const float inv0 = 1.f / ls0, inv1 = 1.f / ls1;

    const int pn0 = n0 + l32, pn1 = n0 + 32 + l32;
    const int i0 = pn0 / 24, j0 = pn0 - i0 * 24;
    const int i1 = pn1 / 24, j1 = pn1 - i1 * 24;
    const size_t gb0 = bbase + (size_t)(a + 8 * i0) * 192 + (c0 + 8 * j0);
    const size_t gb1 = bbase + (size_t)(a + 8 * i1) * 192 + (c0 + 8 * j1);

    #pragma unroll
    for (int r = 0; r < 16; ++r) {
        const int cA = (r & 3) + 8 * (r >> 2) + 4 * h;
        const int cB = 32 + cA;
        const size_t iA0 = gb0 + (size_t)cA * HW;
        const size_t iB0 = gb0 + (size_t)cB * HW;
        const size_t iA1 = gb1 + (size_t)cA * HW;
        const size_t iB1 = gb1 + (size_t)cB * HW;
        io[iA0] = fmaf(g, accA[r] * inv0, io[iA0]);
        io[iB0] = fmaf(g, accB[r] * inv0, io[iB0]);
        io[iA1] = fmaf(g, accC[r] * inv1, io[iA1]);
        io[iB1] = fmaf(g, accD[r] * inv1, io[iB1]);
    }
}

extern "C" void kernel_launch(void* const* d_in, const int* in_sizes, int n_in,
                              void* d_out, int out_size, void* d_ws, size_t ws_size,
                              hipStream_t stream)
{
    const float* x   = (const float*)d_in[0];
    const float* wq1 = (const float*)d_in[1];
    const float* bq1 = (const float*)d_in[2];
    const float* wk1 = (const float*)d_in[3];
    const float* bk1 = (const float*)d_in[4];
    const float* wv1 = (const float*)d_in[5];
    const float* bv1 = (const float*)d_in[6];
    const float* wq2 = (const float*)d_in[7];
    const float* bq2 = (const float*)d_in[8];
    const float* wk2 = (const float*)d_in[9];
    const float* bk2 = (const float*)d_in[10];
    const float* wv2 = (const float*)d_in[11];
    const float* bv2 = (const float*)d_in[12];
    const float* g1  = (const float*)d_in[13];
    const float* g2  = (const float*)d_in[14];
    float* out = (float*)d_out;
    char* ws = (char*)d_ws;

    attn1_mfma<<<dim3(1152), dim3(256), 0, stream>>>(
        x, wq1, bq1, wk1, bk1, wv1, bv1, g1, out);

    proj2w_kernel<<<dim3(512), dim3(576), 0, stream>>>(
        out, wq2, bq2, wk2, bk2, wv2, bv2, ws);

    attn2c_kernel<<<dim3(512), dim3(576), 0, stream>>>(
        out, ws, g2);
}

// Round 7
// 190.343 us; speedup vs baseline: 1.5101x; 1.2053x over previous
//
#include <hip/hip_runtime.h>
#include <hip/hip_bf16.h>

#define HW 36864  // 192*192

typedef __attribute__((ext_vector_type(8))) short short8;   // 8 x bf16 (4 VGPR)
typedef __attribute__((ext_vector_type(16))) float f32x16;  // 32x32 MFMA C/D

__device__ __forceinline__ float BLO(unsigned u) { return __uint_as_float(u << 16); }
__device__ __forceinline__ float BHI(unsigned u) { return __uint_as_float(u & 0xffff0000u); }
__device__ __forceinline__ unsigned short f2bf(float f) {
    unsigned u = __float_as_uint(f);
    u += 0x7fffu + ((u >> 16) & 1u);   // RNE
    return (unsigned short)(u >> 16);
}
__device__ __forceinline__ unsigned pk2(float lo, float hi) {
    unsigned r;
    asm("v_cvt_pk_bf16_f32 %0, %1, %2" : "=v"(r) : "v"(lo), "v"(hi));
    return r;
}
__device__ __forceinline__ void plswap(unsigned &a, unsigned &b) {
    asm volatile("v_permlane32_swap_b32 %0, %1" : "+v"(a), "+v"(b));
}

union FragW { unsigned u[4]; short8 s; };

// d_ws: Xh [B*HW][64] bf16 NHWC records (128 B/pixel) at offset 0 (37.7 MB).
// attn2f reads Xh (out1) and overwrites the same records with normalized
// attention output (wave reads only its own pixels before writing them).

// ---------------- Block 1: 4x4 window attention + NHWC side-write ------------
__global__ __launch_bounds__(256) void attn1_mfma(
    const float* __restrict__ x,
    const float* __restrict__ wq, const float* __restrict__ bq,
    const float* __restrict__ wk, const float* __restrict__ bk,
    const float* __restrict__ wv, const float* __restrict__ bv,
    const float* __restrict__ gamma, float* __restrict__ out,
    char* __restrict__ xh)
{
    __shared__ char smem[4 * 8192];

    const int tid   = threadIdx.x;
    const int wv_id = tid >> 6;
    const int lane  = tid & 63;
    const int l32   = lane & 31;
    const int h     = lane >> 5;
    char* VsW = smem + wv_id * 8192;

    const int gw0 = blockIdx.x * 16 + wv_id * 4;
    const int b_img = (blockIdx.x * 16) / 2304;   // uniform per block

    f32x16 zf;
    #pragma unroll
    for (int r = 0; r < 16; ++r) zf[r] = 0.f;

    FragW wqkf[4], wvf[2][4];
    {
        const float4* wrow4 = (const float4*)((l32 < 16) ? (wq + l32 * 64)
                                                         : (wk + (l32 - 16) * 64));
        #pragma unroll
        for (int cc = 0; cc < 4; ++cc) {
            const float4 a = wrow4[cc * 4 + 2 * h];
            const float4 b = wrow4[cc * 4 + 2 * h + 1];
            wqkf[cc].u[0] = pk2(a.x, a.y); wqkf[cc].u[1] = pk2(a.z, a.w);
            wqkf[cc].u[2] = pk2(b.x, b.y); wqkf[cc].u[3] = pk2(b.z, b.w);
        }
        #pragma unroll
        for (int ot = 0; ot < 2; ++ot) {
            const float4* wvr4 = (const float4*)(wv + (size_t)(ot * 32 + l32) * 64);
            #pragma unroll
            for (int cc = 0; cc < 4; ++cc) {
                const float4 a = wvr4[cc * 4 + 2 * h];
                const float4 b = wvr4[cc * 4 + 2 * h + 1];
                wvf[ot][cc].u[0] = pk2(a.x, a.y); wvf[ot][cc].u[1] = pk2(a.z, a.w);
                wvf[ot][cc].u[2] = pk2(b.x, b.y); wvf[ot][cc].u[3] = pk2(b.z, b.w);
            }
        }
    }
    float bqv[8], bkv[8], bvv[2][16];
    #pragma unroll
    for (int r = 0; r < 8; ++r) {
        const int c = (r & 3) + 8 * (r >> 2) + 4 * h;
        bqv[r] = bq[c];
        bkv[r] = bk[c];
    }
    #pragma unroll
    for (int ot = 0; ot < 2; ++ot)
        #pragma unroll
        for (int r = 0; r < 16; ++r)
            bvv[ot][r] = bv[ot * 32 + (r & 3) + 8 * (r >> 2) + 4 * h];

    size_t gbt[2], px1[2];
    #pragma unroll
    for (int t = 0; t < 2; ++t) {
        const int gwin = gw0 + 2 * t + (l32 >> 4);
        const int rem = gwin % 2304;
        const int Y = rem / 48, X = rem % 48;
        const int yy = Y * 4 + ((l32 >> 2) & 3);
        const int xx = X * 4 + (l32 & 3);
        gbt[t] = (size_t)b_img * 64 * HW + (size_t)yy * 192 + xx;
        px1[t] = (size_t)b_img * HW + (size_t)yy * 192 + xx;
    }

    FragW qf[2], kf[2];
    #pragma unroll
    for (int t = 0; t < 2; ++t) {
        const size_t gb = gbt[t];
        FragW xw[4];
        #pragma unroll
        for (int cc = 0; cc < 4; ++cc)
            #pragma unroll
            for (int j = 0; j < 4; ++j) {
                const int c = cc * 16 + 8 * h + 2 * j;
                xw[cc].u[j] = pk2(x[gb + (size_t)c * HW], x[gb + (size_t)(c + 1) * HW]);
            }

        f32x16 dqk = zf;
        #pragma unroll
        for (int cc = 0; cc < 4; ++cc)
            dqk = __builtin_amdgcn_mfma_f32_32x32x16_bf16(wqkf[cc].s, xw[cc].s, dqk, 0, 0, 0);

        {
            float q0[8];
            #pragma unroll
            for (int r = 0; r < 8; ++r) q0[r] = dqk[r] + bqv[r];
            unsigned A0 = pk2(q0[0], q0[1]), B0 = pk2(q0[2], q0[3]);
            unsigned C0 = pk2(q0[4], q0[5]), D0 = pk2(q0[6], q0[7]);
            plswap(A0, C0); plswap(B0, D0);
            qf[t].u[0] = A0; qf[t].u[1] = B0; qf[t].u[2] = C0; qf[t].u[3] = D0;
        }
        {
            float k0[8];
            #pragma unroll
            for (int r = 0; r < 8; ++r) k0[r] = dqk[8 + r] + bkv[r];
            unsigned A0 = pk2(k0[0], k0[1]), B0 = pk2(k0[2], k0[3]);
            unsigned C0 = pk2(k0[4], k0[5]), D0 = pk2(k0[6], k0[7]);
            plswap(A0, C0); plswap(B0, D0);
            kf[t].u[0] = A0; kf[t].u[1] = B0; kf[t].u[2] = C0; kf[t].u[3] = D0;
        }

        #pragma unroll
        for (int ot = 0; ot < 2; ++ot) {
            f32x16 dv = zf;
            #pragma unroll
            for (int cc = 0; cc < 4; ++cc)
                dv = __builtin_amdgcn_mfma_f32_32x32x16_bf16(wvf[ot][cc].s, xw[cc].s, dv, 0, 0, 0);
            #pragma unroll
            for (int r = 0; r < 16; ++r) {
                const int ch = ot * 32 + (r & 3) + 8 * (r >> 2) + 4 * h;
                *(unsigned short*)(VsW + ((ch * 128 + 2 * (t * 32 + l32)) ^ ((ch & 7) << 4)))
                    = f2bf(dv[r] + bvv[ot][r]);
            }
        }
    }
    __syncthreads();

    const float g = gamma[0];
    const bool wa = (l32 < 16);

    #pragma unroll
    for (int t = 0; t < 2; ++t) {
        f32x16 sT = __builtin_amdgcn_mfma_f32_32x32x16_bf16(kf[t].s, qf[t].s, zf, 0, 0, 0);

        float e[8];
        #pragma unroll
        for (int j = 0; j < 8; ++j) e[j] = __expf(wa ? sT[j] : sT[8 + j]);
        float ls = ((e[0] + e[1]) + (e[2] + e[3])) + ((e[4] + e[5]) + (e[6] + e[7]));
        ls += __shfl_xor(ls, 32);

        unsigned A0 = pk2(e[0], e[1]), B0 = pk2(e[2], e[3]);
        unsigned C0 = pk2(e[4], e[5]), D0 = pk2(e[6], e[7]);
        plswap(A0, C0); plswap(B0, D0);
        FragW pa, pb;
        pa.u[0] = wa ? A0 : 0u; pa.u[1] = wa ? B0 : 0u;
        pa.u[2] = wa ? C0 : 0u; pa.u[3] = wa ? D0 : 0u;
        pb.u[0] = wa ? 0u : A0; pb.u[1] = wa ? 0u : B0;
        pb.u[2] = wa ? 0u : C0; pb.u[3] = wa ? 0u : D0;

        f32x16 acc0 = zf, acc1 = zf;
        #pragma unroll
        for (int wsx = 0; wsx < 2; ++wsx) {
            const short8 pfrag = wsx ? pb.s : pa.s;
            const int mbase = t * 64 + wsx * 32 + 16 * h;
            const int ch0 = l32, ch1 = 32 + l32;
            const short8 v0 = *(const short8*)(VsW + ((ch0 * 128 + mbase) ^ ((ch0 & 7) << 4)));
            const short8 v1 = *(const short8*)(VsW + ((ch1 * 128 + mbase) ^ ((ch1 & 7) << 4)));
            acc0 = __builtin_amdgcn_mfma_f32_32x32x16_bf16(v0, pfrag, acc0, 0, 0, 0);
            acc1 = __builtin_amdgcn_mfma_f32_32x32x16_bf16(v1, pfrag, acc1, 0, 0, 0);
        }

        const float inv = 1.f / ls;
        const size_t gb = gbt[t];
        float o0[16], o1[16];
        #pragma unroll
        for (int r = 0; r < 16; ++r) {
            const int cA = (r & 3) + 8 * (r >> 2) + 4 * h;
            const int cB = 32 + cA;
            const size_t iA = gb + (size_t)cA * HW;
            const size_t iB = gb + (size_t)cB * HW;
            o0[r] = fmaf(g, acc0[r] * inv, x[iA]);
            o1[r] = fmaf(g, acc1[r] * inv, x[iB]);
            out[iA] = o0[r];
            out[iB] = o1[r];
        }

        // NHWC bf16 side-write of out1 (8 x uint2 per lane, record-local)
        char* arec = xh + px1[t] * 128;
        #pragma unroll
        for (int q = 0; q < 4; ++q) {
            const int cb = 8 * q + 4 * h;        // o[4q..4q+3] = ch cb..cb+3
            uint2 wA; wA.x = pk2(o0[4*q], o0[4*q+1]); wA.y = pk2(o0[4*q+2], o0[4*q+3]);
            *(uint2*)(arec + cb * 2) = wA;
            uint2 wB; wB.x = pk2(o1[4*q], o1[4*q+1]); wB.y = pk2(o1[4*q+2], o1[4*q+3]);
            *(uint2*)(arec + 64 + cb * 2) = wB;
        }
    }
}

// ---------------- attn2f: fused 8x8 chess proj + attention (NHWC in/out) -----
// One block per window, 576 thr = 9 waves. Reads Xh (out1 NHWC bf16) for its
// own 576 pixels, writes normalized attention back over the same records.
#define KT_OFF 0
#define VS_OFF 18432

__global__ __launch_bounds__(576) void attn2f_kernel(
    char* __restrict__ xh,
    const float* __restrict__ wq, const float* __restrict__ bq,
    const float* __restrict__ wk, const float* __restrict__ bk,
    const float* __restrict__ wv, const float* __restrict__ bv)
{
    __shared__ char smem[92160];   // Kt 18432 + Vs 73728

    const int wid = blockIdx.x;
    const int b  = wid >> 6;
    const int a  = wid & 7;
    const int c0 = (wid >> 3) & 7;

    const int tid = threadIdx.x;
    const int wv_id = tid >> 6;
    const int l32 = tid & 31;
    const int h   = (tid >> 5) & 1;
    const int n0  = wv_id * 64;

    f32x16 zf;
    #pragma unroll
    for (int r = 0; r < 16; ++r) zf[r] = 0.f;

    // weight/bias fragments (float4 loads)
    FragW wqkf[4], wvf[2][4];
    {
        const float4* wrow4 = (const float4*)((l32 < 16) ? (wq + l32 * 64)
                                                         : (wk + (l32 - 16) * 64));
        #pragma unroll
        for (int cc = 0; cc < 4; ++cc) {
            const float4 a4 = wrow4[cc * 4 + 2 * h];
            const float4 b4 = wrow4[cc * 4 + 2 * h + 1];
            wqkf[cc].u[0] = pk2(a4.x, a4.y); wqkf[cc].u[1] = pk2(a4.z, a4.w);
            wqkf[cc].u[2] = pk2(b4.x, b4.y); wqkf[cc].u[3] = pk2(b4.z, b4.w);
        }
        #pragma unroll
        for (int ot = 0; ot < 2; ++ot) {
            const float4* wvr4 = (const float4*)(wv + (size_t)(ot * 32 + l32) * 64);
            #pragma unroll
            for (int cc = 0; cc < 4; ++cc) {
                const float4 a4 = wvr4[cc * 4 + 2 * h];
                const float4 b4 = wvr4[cc * 4 + 2 * h + 1];
                wvf[ot][cc].u[0] = pk2(a4.x, a4.y); wvf[ot][cc].u[1] = pk2(a4.z, a4.w);
                wvf[ot][cc].u[2] = pk2(b4.x, b4.y); wvf[ot][cc].u[3] = pk2(b4.z, b4.w);
            }
        }
    }
    float bias_qk[16], bvv[2][16];
    #pragma unroll
    for (int r = 0; r < 8; ++r) {
        const int c = (r & 3) + 8 * (r >> 2) + 4 * h;
        bias_qk[r] = bq[c];
        bias_qk[8 + r] = bk[c];
    }
    #pragma unroll
    for (int ot = 0; ot < 2; ++ot)
        #pragma unroll
        for (int r = 0; r < 16; ++r)
            bvv[ot][r] = bv[ot * 32 + (r & 3) + 8 * (r >> 2) + 4 * h];

    // ---- projection phase (X from NHWC records, coalesced) ------------------
    size_t prec[2];
    FragW qfr[2];
    #pragma unroll
    for (int t = 0; t < 2; ++t) {
        const int m = n0 + t * 32 + l32;
        const int i = m / 24, j = m - i * 24;
        prec[t] = ((size_t)b * HW + (size_t)(a + 8 * i) * 192 + (c0 + 8 * j)) * 128;
        const char* rec = xh + prec[t];

        FragW xw[4];
        #pragma unroll
        for (int cc = 0; cc < 4; ++cc)
            xw[cc].s = *(const short8*)(rec + cc * 32 + 16 * h);

        f32x16 dqk = zf;
        #pragma unroll
        for (int cc = 0; cc < 4; ++cc)
            dqk = __builtin_amdgcn_mfma_f32_32x32x16_bf16(wqkf[cc].s, xw[cc].s, dqk, 0, 0, 0);

        {   // Q B-frag
            float q0[8];
            #pragma unroll
            for (int r = 0; r < 8; ++r) q0[r] = dqk[r] + bias_qk[r];
            unsigned A0 = pk2(q0[0], q0[1]), B0 = pk2(q0[2], q0[3]);
            unsigned C0 = pk2(q0[4], q0[5]), D0 = pk2(q0[6], q0[7]);
            plswap(A0, C0); plswap(B0, D0);
            qfr[t].u[0] = A0; qfr[t].u[1] = B0; qfr[t].u[2] = C0; qfr[t].u[3] = D0;
        }
        // K rows -> Kt LDS (swizzled)
        #pragma unroll
        for (int r = 8; r < 16; ++r) {
            const int c = (r & 3) + 8 * ((r >> 2) & 1) + 4 * h;
            *(unsigned short*)(smem + KT_OFF + ((m * 32 + 2 * c) ^ (((m >> 2) & 3) << 4)))
                = f2bf(dqk[r] + bias_qk[r]);
        }
        // V -> Vs LDS (swizzled)
        #pragma unroll
        for (int ot = 0; ot < 2; ++ot) {
            f32x16 dv = zf;
            #pragma unroll
            for (int cc = 0; cc < 4; ++cc)
                dv = __builtin_amdgcn_mfma_f32_32x32x16_bf16(wvf[ot][cc].s, xw[cc].s, dv, 0, 0, 0);
            #pragma unroll
            for (int r = 0; r < 16; ++r) {
                const int ch = ot * 32 + (r & 3) + 8 * (r >> 2) + 4 * h;
                *(unsigned short*)(smem + VS_OFF + ((ch * 1152 + 2 * m) ^ ((ch & 7) << 4)))
                    = f2bf(dv[r] + bvv[ot][r]);
            }
        }
    }
    __syncthreads();

    // ---- attention loop (verbatim round-3 structure) -------------------------
    const short8 qf0 = qfr[0].s, qf1 = qfr[1].s;
    f32x16 accA = zf, accB = zf, accC = zf, accD = zf;
    float ls0 = 0.f, ls1 = 0.f;
    const int chA = l32, chB = 32 + l32;
    const int swzA = (chA & 7) << 4, swzB = (chB & 7) << 4;

    #pragma unroll 1
    for (int mt = 0; mt < 18; ++mt) {
        const int m0 = mt * 32;
        const int mr = m0 + l32;
        const short8 kf = *(const short8*)(smem + KT_OFF + ((mr * 32 + 16 * h) ^ (((mr >> 2) & 3) << 4)));
        f32x16 s0 = __builtin_amdgcn_mfma_f32_32x32x16_bf16(kf, qf0, zf, 0, 0, 0);
        f32x16 s1 = __builtin_amdgcn_mfma_f32_32x32x16_bf16(kf, qf1, zf, 0, 0, 0);

        const short8 vA0 = *(const short8*)(smem + VS_OFF + ((chA * 1152 + 2 * (m0 + 8 * h)) ^ swzA));
        const short8 vA1 = *(const short8*)(smem + VS_OFF + ((chA * 1152 + 2 * (m0 + 16 + 8 * h)) ^ swzA));
        const short8 vB0 = *(const short8*)(smem + VS_OFF + ((chB * 1152 + 2 * (m0 + 8 * h)) ^ swzB));
        const short8 vB1 = *(const short8*)(smem + VS_OFF + ((chB * 1152 + 2 * (m0 + 16 + 8 * h)) ^ swzB));

        #pragma unroll
        for (int r = 0; r < 16; ++r) s0[r] = __expf(s0[r]);
        #pragma unroll
        for (int r = 0; r < 16; ++r) s1[r] = __expf(s1[r]);
        ls0 += ((s0[0]+s0[1])+(s0[2]+s0[3])) + ((s0[4]+s0[5])+(s0[6]+s0[7]))
             + ((s0[8]+s0[9])+(s0[10]+s0[11])) + ((s0[12]+s0[13])+(s0[14]+s0[15]));
        ls1 += ((s1[0]+s1[1])+(s1[2]+s1[3])) + ((s1[4]+s1[5])+(s1[6]+s1[7]))
             + ((s1[8]+s1[9])+(s1[10]+s1[11])) + ((s1[12]+s1[13])+(s1[14]+s1[15]));

        FragW pf00, pf01, pf10, pf11;
        {
            unsigned A0 = pk2(s0[0], s0[1]), B0 = pk2(s0[2], s0[3]);
            unsigned C0 = pk2(s0[4], s0[5]), D0 = pk2(s0[6], s0[7]);
            plswap(A0, C0); plswap(B0, D0);
            pf00.u[0] = A0; pf00.u[1] = B0; pf00.u[2] = C0; pf00.u[3] = D0;
            unsigned E0 = pk2(s0[8], s0[9]),  F0 = pk2(s0[10], s0[11]);
            unsigned G0 = pk2(s0[12], s0[13]), H0 = pk2(s0[14], s0[15]);
            plswap(E0, G0); plswap(F0, H0);
            pf01.u[0] = E0; pf01.u[1] = F0; pf01.u[2] = G0; pf01.u[3] = H0;
            unsigned A1 = pk2(s1[0], s1[1]), B1 = pk2(s1[2], s1[3]);
            unsigned C1 = pk2(s1[4], s1[5]), D1 = pk2(s1[6], s1[7]);
            plswap(A1, C1); plswap(B1, D1);
            pf10.u[0] = A1; pf10.u[1] = B1; pf10.u[2] = C1; pf10.u[3] = D1;
            unsigned E1 = pk2(s1[8], s1[9]),  F1 = pk2(s1[10], s1[11]);
            unsigned G1 = pk2(s1[12], s1[13]), H1 = pk2(s1[14], s1[15]);
            plswap(E1, G1); plswap(F1, H1);
            pf11.u[0] = E1; pf11.u[1] = F1; pf11.u[2] = G1; pf11.u[3] = H1;
        }

        accA = __builtin_amdgcn_mfma_f32_32x32x16_bf16(vA0, pf00.s, accA, 0, 0, 0);
        accA = __builtin_amdgcn_mfma_f32_32x32x16_bf16(vA1, pf01.s, accA, 0, 0, 0);
        accB = __builtin_amdgcn_mfma_f32_32x32x16_bf16(vB0, pf00.s, accB, 0, 0, 0);
        accB = __builtin_amdgcn_mfma_f32_32x32x16_bf16(vB1, pf01.s, accB, 0, 0, 0);
        accC = __builtin_amdgcn_mfma_f32_32x32x16_bf16(vA0, pf10.s, accC, 0, 0, 0);
        accC = __builtin_amdgcn_mfma_f32_32x32x16_bf16(vA1, pf11.s, accC, 0, 0, 0);
        accD = __builtin_amdgcn_mfma_f32_32x32x16_bf16(vB0, pf10.s, accD, 0, 0, 0);
        accD = __builtin_amdgcn_mfma_f32_32x32x16_bf16(vB1, pf11.s, accD, 0, 0, 0);
    }

    ls0 += __shfl_xor(ls0, 32);
    ls1 += __shfl_xor(ls1, 32);
    const float inv0 = 1.f / ls0, inv1 = 1.f / ls1;

    // normalized attention -> NHWC bf16, overwriting this wave's own records
    char* a0 = xh + prec[0];
    char* a1 = xh + prec[1];
    #pragma unroll
    for (int q = 0; q < 4; ++q) {
        const int cb = 8 * q + 4 * h;
        uint2 wA; wA.x = pk2(accA[4*q]*inv0, accA[4*q+1]*inv0);
                  wA.y = pk2(accA[4*q+2]*inv0, accA[4*q+3]*inv0);
        *(uint2*)(a0 + cb * 2) = wA;
        uint2 wB; wB.x = pk2(accB[4*q]*inv0, accB[4*q+1]*inv0);
                  wB.y = pk2(accB[4*q+2]*inv0, accB[4*q+3]*inv0);
        *(uint2*)(a0 + 64 + cb * 2) = wB;
        uint2 wC; wC.x = pk2(accC[4*q]*inv1, accC[4*q+1]*inv1);
                  wC.y = pk2(accC[4*q+2]*inv1, accC[4*q+3]*inv1);
        *(uint2*)(a1 + cb * 2) = wC;
        uint2 wD; wD.x = pk2(accD[4*q]*inv1, accD[4*q+1]*inv1);
                  wD.y = pk2(accD[4*q+2]*inv1, accD[4*q+3]*inv1);
        *(uint2*)(a1 + 64 + cb * 2) = wD;
    }
}

// ---------------- final: out = g2 * Att(NHWC->NCHW) + out1 (in-place) --------
// Block = one image row (b,y): 256 thr. Att row (192 px x 128 B) staged in LDS
// with 16B-granule XOR swizzle; writes fully coalesced per (ch, x-range).
__global__ __launch_bounds__(256) void final_kernel(
    float* __restrict__ out, const char* __restrict__ xh,
    const float* __restrict__ gamma)
{
    __shared__ char smem[24576];

    const int bid = blockIdx.x;
    const int b = bid / 192, y = bid % 192;
    const int tid = threadIdx.x;

    const char* src = xh + ((size_t)b * HW + (size_t)y * 192) * 128;
    #pragma unroll
    for (int k = 0; k < 6; ++k) {
        const int off = k * 4096 + tid * 16;
        const int xq = off >> 7;               // pixel x
        const int gq = (off >> 4) & 7;         // 16B chunk in record
        const short8 v = *(const short8*)(src + off);
        *(short8*)(smem + (xq << 7) + (((gq ^ (xq & 7)) << 4))) = v;
    }
    __syncthreads();

    const float g2 = gamma[0];
    const int w = tid >> 6, lane = tid & 63;
    const size_t rowbase = (size_t)b * 64 * HW + (size_t)y * 192;

    #pragma unroll
    for (int it = 0; it < 24; ++it) {
        const int tt = it * 4 + w;             // 0..95
        const int chp = tt & 31;               // channel pair
        const int xb = tt >> 5;                // 0..2
        const int xx = xb * 64 + lane;
        const int byte_in_rec = chp * 4;
        const int gq = byte_in_rec >> 4;
        const unsigned v = *(const unsigned*)(smem + (xx << 7)
                            + ((gq ^ (xx & 7)) << 4) + (byte_in_rec & 15));
        const size_t o0 = rowbase + (size_t)(2 * chp) * HW + xx;
        out[o0]      = fmaf(g2, BLO(v), out[o0]);
        out[o0 + HW] = fmaf(g2, BHI(v), out[o0 + HW]);
    }
}

extern "C" void kernel_launch(void* const* d_in, const int* in_sizes, int n_in,
                              void* d_out, int out_size, void* d_ws, size_t ws_size,
                              hipStream_t stream)
{
    const float* x   = (const float*)d_in[0];
    const float* wq1 = (const float*)d_in[1];
    const float* bq1 = (const float*)d_in[2];
    const float* wk1 = (const float*)d_in[3];
    const float* bk1 = (const float*)d_in[4];
    const float* wv1 = (const float*)d_in[5];
    const float* bv1 = (const float*)d_in[6];
    const float* wq2 = (const float*)d_in[7];
    const float* bq2 = (const float*)d_in[8];
    const float* wk2 = (const float*)d_in[9];
    const float* bk2 = (const float*)d_in[10];
    const float* wv2 = (const float*)d_in[11];
    const float* bv2 = (const float*)d_in[12];
    const float* g1  = (const float*)d_in[13];
    const float* g2  = (const float*)d_in[14];
    float* out = (float*)d_out;
    char* xh = (char*)d_ws;

    attn1_mfma<<<dim3(1152), dim3(256), 0, stream>>>(
        x, wq1, bq1, wk1, bk1, wv1, bv1, g1, out, xh);

    attn2f_kernel<<<dim3(512), dim3(576), 0, stream>>>(
        xh, wq2, bq2, wk2, bk2, wv2, bv2);

    final_kernel<<<dim3(1536), dim3(256), 0, stream>>>(
        out, xh, g2);
}

// Round 8
// 149.923 us; speedup vs baseline: 1.9172x; 1.2696x over previous
//
#include <hip/hip_runtime.h>
#include <hip/hip_bf16.h>

#define HW 36864  // 192*192

typedef __attribute__((ext_vector_type(8))) short short8;   // 8 x bf16 (4 VGPR)
typedef __attribute__((ext_vector_type(16))) float f32x16;  // 32x32 MFMA C/D

__device__ __forceinline__ float BLO(unsigned u) { return __uint_as_float(u << 16); }
__device__ __forceinline__ float BHI(unsigned u) { return __uint_as_float(u & 0xffff0000u); }
__device__ __forceinline__ unsigned short f2bf(float f) {
    unsigned u = __float_as_uint(f);
    u += 0x7fffu + ((u >> 16) & 1u);   // RNE
    return (unsigned short)(u >> 16);
}
__device__ __forceinline__ unsigned pk2(float lo, float hi) {
    unsigned r;
    asm("v_cvt_pk_bf16_f32 %0, %1, %2" : "=v"(r) : "v"(lo), "v"(hi));
    return r;
}
__device__ __forceinline__ void plswap(unsigned &a, unsigned &b) {
    asm volatile("v_permlane32_swap_b32 %0, %1" : "+v"(a), "+v"(b));
}

union FragW { unsigned u[4]; short8 s; };

// d_ws: Xh [B*HW][64ch] bf16 NHWC records, 128 B/pixel (37.75 MB total).
// Lifecycle: to_nhwc writes x; attn1n overwrites with out1 (in-place, per-wave
// own records); attn2n overwrites with FINAL = g2*att2 + out1; to_nchw -> d_out.

// ---------------- K1: x NCHW f32 -> NHWC bf16 records ------------------------
__global__ __launch_bounds__(256) void to_nhwc_kernel(
    const float* __restrict__ x, char* __restrict__ xh)
{
    __shared__ unsigned lds[32 * 193];
    const int bid = blockIdx.x;
    const int b = bid / 192, y = bid % 192;
    const int tid = threadIdx.x;
    const int cp = tid >> 3, xq8 = tid & 7;

    const float4* rA = (const float4*)(x + ((size_t)b * 64 + 2 * cp) * HW + (size_t)y * 192);
    const float4* rB = (const float4*)(x + ((size_t)b * 64 + 2 * cp + 1) * HW + (size_t)y * 192);
    #pragma unroll
    for (int i = 0; i < 6; ++i) {
        const int f = 8 * i + xq8;
        const float4 a = rA[f];
        const float4 c = rB[f];
        const int px = f * 4;
        lds[cp * 193 + px + 0] = pk2(a.x, c.x);
        lds[cp * 193 + px + 1] = pk2(a.y, c.y);
        lds[cp * 193 + px + 2] = pk2(a.z, c.z);
        lds[cp * 193 + px + 3] = pk2(a.w, c.w);
    }
    __syncthreads();

    char* dst = xh + ((size_t)b * HW + (size_t)y * 192) * 128;
    #pragma unroll
    for (int j = 0; j < 6; ++j) {
        const int idx = j * 256 + tid;
        const int px = idx >> 3, q = idx & 7;
        uint4 v;
        v.x = lds[(4 * q + 0) * 193 + px];
        v.y = lds[(4 * q + 1) * 193 + px];
        v.z = lds[(4 * q + 2) * 193 + px];
        v.w = lds[(4 * q + 3) * 193 + px];
        *(uint4*)(dst + px * 128 + q * 16) = v;
    }
}

// ---------------- K2: 4x4 window attention, NHWC in-place --------------------
// Block = 16 windows (4 waves x 4 windows); wave reads only its own 64 records.
__global__ __launch_bounds__(256) void attn1n_kernel(
    char* __restrict__ xh,
    const float* __restrict__ wq, const float* __restrict__ bq,
    const float* __restrict__ wk, const float* __restrict__ bk,
    const float* __restrict__ wv, const float* __restrict__ bv,
    const float* __restrict__ gamma)
{
    __shared__ char smem[4 * 8192];

    const int tid   = threadIdx.x;
    const int wv_id = tid >> 6;
    const int lane  = tid & 63;
    const int l32   = lane & 31;
    const int h     = lane >> 5;
    char* VsW = smem + wv_id * 8192;

    const int gw0 = blockIdx.x * 16 + wv_id * 4;

    f32x16 zf;
    #pragma unroll
    for (int r = 0; r < 16; ++r) zf[r] = 0.f;

    // weight/bias fragments (float4 loads)
    FragW wqkf[4], wvf[2][4];
    {
        const float4* wrow4 = (const float4*)((l32 < 16) ? (wq + l32 * 64)
                                                         : (wk + (l32 - 16) * 64));
        #pragma unroll
        for (int cc = 0; cc < 4; ++cc) {
            const float4 a = wrow4[cc * 4 + 2 * h];
            const float4 b = wrow4[cc * 4 + 2 * h + 1];
            wqkf[cc].u[0] = pk2(a.x, a.y); wqkf[cc].u[1] = pk2(a.z, a.w);
            wqkf[cc].u[2] = pk2(b.x, b.y); wqkf[cc].u[3] = pk2(b.z, b.w);
        }
        #pragma unroll
        for (int ot = 0; ot < 2; ++ot) {
            const float4* wvr4 = (const float4*)(wv + (size_t)(ot * 32 + l32) * 64);
            #pragma unroll
            for (int cc = 0; cc < 4; ++cc) {
                const float4 a = wvr4[cc * 4 + 2 * h];
                const float4 b = wvr4[cc * 4 + 2 * h + 1];
                wvf[ot][cc].u[0] = pk2(a.x, a.y); wvf[ot][cc].u[1] = pk2(a.z, a.w);
                wvf[ot][cc].u[2] = pk2(b.x, b.y); wvf[ot][cc].u[3] = pk2(b.z, b.w);
            }
        }
    }
    float bqv[8], bkv[8], bvv[2][16];
    #pragma unroll
    for (int r = 0; r < 8; ++r) {
        const int c = (r & 3) + 8 * (r >> 2) + 4 * h;
        bqv[r] = bq[c];
        bkv[r] = bk[c];
    }
    #pragma unroll
    for (int ot = 0; ot < 2; ++ot)
        #pragma unroll
        for (int r = 0; r < 16; ++r)
            bvv[ot][r] = bv[ot * 32 + (r & 3) + 8 * (r >> 2) + 4 * h];

    // identity A-frags: I_lo lifts chunk ch 0..15 -> rows 0..15, I_hi -> rows 16..31
    FragW Ilo, Ihi;
    #pragma unroll
    for (int j = 0; j < 4; ++j) {
        const int k0 = 8 * h + 2 * j;
        unsigned lo  = (l32 == k0)      ? 0x3F80u : 0u;
        unsigned hi  = (l32 == k0 + 1)  ? 0x3F80u : 0u;
        Ilo.u[j] = lo | (hi << 16);
        unsigned lo2 = (l32 == 16 + k0)     ? 0x3F80u : 0u;
        unsigned hi2 = (l32 == 16 + k0 + 1) ? 0x3F80u : 0u;
        Ihi.u[j] = lo2 | (hi2 << 16);
    }

    size_t px1[2];
    #pragma unroll
    for (int t = 0; t < 2; ++t) {
        const int gwin = gw0 + 2 * t + (l32 >> 4);
        const int b = gwin / 2304;
        const int rem = gwin % 2304;
        const int Y = rem / 48, X = rem % 48;
        const int yy = Y * 4 + ((l32 >> 2) & 3);
        const int xx = X * 4 + (l32 & 3);
        px1[t] = ((size_t)b * HW + (size_t)yy * 192 + xx) * 128;
    }

    FragW qf[2], kf[2];
    #pragma unroll
    for (int t = 0; t < 2; ++t) {
        const char* rec = xh + px1[t];
        FragW xw[4];
        #pragma unroll
        for (int cc = 0; cc < 4; ++cc)
            xw[cc].s = *(const short8*)(rec + cc * 32 + 16 * h);

        f32x16 dqk = zf;
        #pragma unroll
        for (int cc = 0; cc < 4; ++cc)
            dqk = __builtin_amdgcn_mfma_f32_32x32x16_bf16(wqkf[cc].s, xw[cc].s, dqk, 0, 0, 0);

        {
            float q0[8];
            #pragma unroll
            for (int r = 0; r < 8; ++r) q0[r] = dqk[r] + bqv[r];
            unsigned A0 = pk2(q0[0], q0[1]), B0 = pk2(q0[2], q0[3]);
            unsigned C0 = pk2(q0[4], q0[5]), D0 = pk2(q0[6], q0[7]);
            plswap(A0, C0); plswap(B0, D0);
            qf[t].u[0] = A0; qf[t].u[1] = B0; qf[t].u[2] = C0; qf[t].u[3] = D0;
        }
        {
            float k0[8];
            #pragma unroll
            for (int r = 0; r < 8; ++r) k0[r] = dqk[8 + r] + bkv[r];
            unsigned A0 = pk2(k0[0], k0[1]), B0 = pk2(k0[2], k0[3]);
            unsigned C0 = pk2(k0[4], k0[5]), D0 = pk2(k0[6], k0[7]);
            plswap(A0, C0); plswap(B0, D0);
            kf[t].u[0] = A0; kf[t].u[1] = B0; kf[t].u[2] = C0; kf[t].u[3] = D0;
        }

        #pragma unroll
        for (int ot = 0; ot < 2; ++ot) {
            f32x16 dv = zf;
            #pragma unroll
            for (int cc = 0; cc < 4; ++cc)
                dv = __builtin_amdgcn_mfma_f32_32x32x16_bf16(wvf[ot][cc].s, xw[cc].s, dv, 0, 0, 0);
            #pragma unroll
            for (int r = 0; r < 16; ++r) {
                const int ch = ot * 32 + (r & 3) + 8 * (r >> 2) + 4 * h;
                *(unsigned short*)(VsW + ((ch * 128 + 2 * (t * 32 + l32)) ^ ((ch & 7) << 4)))
                    = f2bf(dv[r] + bvv[ot][r]);
            }
        }
    }
    __syncthreads();

    const float g = gamma[0];
    const bool wa = (l32 < 16);

    #pragma unroll
    for (int t = 0; t < 2; ++t) {
        f32x16 sT = __builtin_amdgcn_mfma_f32_32x32x16_bf16(kf[t].s, qf[t].s, zf, 0, 0, 0);

        float e[8];
        #pragma unroll
        for (int j = 0; j < 8; ++j) e[j] = __expf(wa ? sT[j] : sT[8 + j]);
        float ls = ((e[0] + e[1]) + (e[2] + e[3])) + ((e[4] + e[5]) + (e[6] + e[7]));
        ls += __shfl_xor(ls, 32);

        unsigned A0 = pk2(e[0], e[1]), B0 = pk2(e[2], e[3]);
        unsigned C0 = pk2(e[4], e[5]), D0 = pk2(e[6], e[7]);
        plswap(A0, C0); plswap(B0, D0);
        FragW pa, pb;
        pa.u[0] = wa ? A0 : 0u; pa.u[1] = wa ? B0 : 0u;
        pa.u[2] = wa ? C0 : 0u; pa.u[3] = wa ? D0 : 0u;
        pb.u[0] = wa ? 0u : A0; pb.u[1] = wa ? 0u : B0;
        pb.u[2] = wa ? 0u : C0; pb.u[3] = wa ? 0u : D0;

        f32x16 acc0 = zf, acc1 = zf;
        #pragma unroll
        for (int wsx = 0; wsx < 2; ++wsx) {
            const short8 pfrag = wsx ? pb.s : pa.s;
            const int mbase = t * 64 + wsx * 32 + 16 * h;
            const int ch0 = l32, ch1 = 32 + l32;
            const short8 v0 = *(const short8*)(VsW + ((ch0 * 128 + mbase) ^ ((ch0 & 7) << 4)));
            const short8 v1 = *(const short8*)(VsW + ((ch1 * 128 + mbase) ^ ((ch1 & 7) << 4)));
            acc0 = __builtin_amdgcn_mfma_f32_32x32x16_bf16(v0, pfrag, acc0, 0, 0, 0);
            acc1 = __builtin_amdgcn_mfma_f32_32x32x16_bf16(v1, pfrag, acc1, 0, 0, 0);
        }

        const float inv = 1.f / ls;

        // residual from own record via identity MFMA (exact D-layout)
        char* rec = xh + px1[t];
        FragW x0, x1, x2, x3;
        x0.s = *(const short8*)(rec + 0 * 32 + 16 * h);
        x1.s = *(const short8*)(rec + 1 * 32 + 16 * h);
        x2.s = *(const short8*)(rec + 2 * 32 + 16 * h);
        x3.s = *(const short8*)(rec + 3 * 32 + 16 * h);
        f32x16 r01 = __builtin_amdgcn_mfma_f32_32x32x16_bf16(Ihi.s, x1.s, zf, 0, 0, 0);
        r01 = __builtin_amdgcn_mfma_f32_32x32x16_bf16(Ilo.s, x0.s, r01, 0, 0, 0);
        f32x16 r23 = __builtin_amdgcn_mfma_f32_32x32x16_bf16(Ihi.s, x3.s, zf, 0, 0, 0);
        r23 = __builtin_amdgcn_mfma_f32_32x32x16_bf16(Ilo.s, x2.s, r23, 0, 0, 0);

        #pragma unroll
        for (int q = 0; q < 4; ++q) {
            const float a0 = fmaf(g, acc0[4*q+0] * inv, r01[4*q+0]);
            const float a1 = fmaf(g, acc0[4*q+1] * inv, r01[4*q+1]);
            const float a2 = fmaf(g, acc0[4*q+2] * inv, r01[4*q+2]);
            const float a3 = fmaf(g, acc0[4*q+3] * inv, r01[4*q+3]);
            uint2 wA; wA.x = pk2(a0, a1); wA.y = pk2(a2, a3);
            *(uint2*)(rec + 16 * q + 8 * h) = wA;
            const float b0 = fmaf(g, acc1[4*q+0] * inv, r23[4*q+0]);
            const float b1 = fmaf(g, acc1[4*q+1] * inv, r23[4*q+1]);
            const float b2 = fmaf(g, acc1[4*q+2] * inv, r23[4*q+2]);
            const float b3 = fmaf(g, acc1[4*q+3] * inv, r23[4*q+3]);
            uint2 wB; wB.x = pk2(b0, b1); wB.y = pk2(b2, b3);
            *(uint2*)(rec + 64 + 16 * q + 8 * h) = wB;
        }
    }
}

// ---------------- K3: 8x8 chess proj + attention + final fold, in-place ------
#define KT_OFF 0
#define VS_OFF 18432

__global__ __launch_bounds__(576) void attn2n_kernel(
    char* __restrict__ xh,
    const float* __restrict__ wq, const float* __restrict__ bq,
    const float* __restrict__ wk, const float* __restrict__ bk,
    const float* __restrict__ wv, const float* __restrict__ bv,
    const float* __restrict__ gamma)
{
    __shared__ char smem[92160];   // Kt 18432 + Vs 73728

    const int wid = blockIdx.x;
    const int b  = wid >> 6;
    const int a  = wid & 7;
    const int c0 = (wid >> 3) & 7;

    const int tid = threadIdx.x;
    const int wv_id = tid >> 6;
    const int l32 = tid & 31;
    const int h   = (tid >> 5) & 1;
    const int n0  = wv_id * 64;

    f32x16 zf;
    #pragma unroll
    for (int r = 0; r < 16; ++r) zf[r] = 0.f;

    FragW wqkf[4], wvf[2][4];
    {
        const float4* wrow4 = (const float4*)((l32 < 16) ? (wq + l32 * 64)
                                                         : (wk + (l32 - 16) * 64));
        #pragma unroll
        for (int cc = 0; cc < 4; ++cc) {
            const float4 a4 = wrow4[cc * 4 + 2 * h];
            const float4 b4 = wrow4[cc * 4 + 2 * h + 1];
            wqkf[cc].u[0] = pk2(a4.x, a4.y); wqkf[cc].u[1] = pk2(a4.z, a4.w);
            wqkf[cc].u[2] = pk2(b4.x, b4.y); wqkf[cc].u[3] = pk2(b4.z, b4.w);
        }
        #pragma unroll
        for (int ot = 0; ot < 2; ++ot) {
            const float4* wvr4 = (const float4*)(wv + (size_t)(ot * 32 + l32) * 64);
            #pragma unroll
            for (int cc = 0; cc < 4; ++cc) {
                const float4 a4 = wvr4[cc * 4 + 2 * h];
                const float4 b4 = wvr4[cc * 4 + 2 * h + 1];
                wvf[ot][cc].u[0] = pk2(a4.x, a4.y); wvf[ot][cc].u[1] = pk2(a4.z, a4.w);
                wvf[ot][cc].u[2] = pk2(b4.x, b4.y); wvf[ot][cc].u[3] = pk2(b4.z, b4.w);
            }
        }
    }
    float bias_qk[16], bvv[2][16];
    #pragma unroll
    for (int r = 0; r < 8; ++r) {
        const int c = (r & 3) + 8 * (r >> 2) + 4 * h;
        bias_qk[r] = bq[c];
        bias_qk[8 + r] = bk[c];
    }
    #pragma unroll
    for (int ot = 0; ot < 2; ++ot)
        #pragma unroll
        for (int r = 0; r < 16; ++r)
            bvv[ot][r] = bv[ot * 32 + (r & 3) + 8 * (r >> 2) + 4 * h];

    // identity A-frags
    FragW Ilo, Ihi;
    #pragma unroll
    for (int j = 0; j < 4; ++j) {
        const int k0 = 8 * h + 2 * j;
        unsigned lo  = (l32 == k0)      ? 0x3F80u : 0u;
        unsigned hi  = (l32 == k0 + 1)  ? 0x3F80u : 0u;
        Ilo.u[j] = lo | (hi << 16);
        unsigned lo2 = (l32 == 16 + k0)     ? 0x3F80u : 0u;
        unsigned hi2 = (l32 == 16 + k0 + 1) ? 0x3F80u : 0u;
        Ihi.u[j] = lo2 | (hi2 << 16);
    }

    size_t prec[2];
    FragW qfr[2];
    #pragma unroll
    for (int t = 0; t < 2; ++t) {
        const int m = n0 + t * 32 + l32;
        const int i = m / 24, j = m - i * 24;
        prec[t] = ((size_t)b * HW + (size_t)(a + 8 * i) * 192 + (c0 + 8 * j)) * 128;
        const char* rec = xh + prec[t];

        FragW xw[4];
        #pragma unroll
        for (int cc = 0; cc < 4; ++cc)
            xw[cc].s = *(const short8*)(rec + cc * 32 + 16 * h);

        f32x16 dqk = zf;
        #pragma unroll
        for (int cc = 0; cc < 4; ++cc)
            dqk = __builtin_amdgcn_mfma_f32_32x32x16_bf16(wqkf[cc].s, xw[cc].s, dqk, 0, 0, 0);

        {   // Q B-frag
            float q0[8];
            #pragma unroll
            for (int r = 0; r < 8; ++r) q0[r] = dqk[r] + bias_qk[r];
            unsigned A0 = pk2(q0[0], q0[1]), B0 = pk2(q0[2], q0[3]);
            unsigned C0 = pk2(q0[4], q0[5]), D0 = pk2(q0[6], q0[7]);
            plswap(A0, C0); plswap(B0, D0);
            qfr[t].u[0] = A0; qfr[t].u[1] = B0; qfr[t].u[2] = C0; qfr[t].u[3] = D0;
        }
        #pragma unroll
        for (int r = 8; r < 16; ++r) {
            const int c = (r & 3) + 8 * ((r >> 2) & 1) + 4 * h;
            *(unsigned short*)(smem + KT_OFF + ((m * 32 + 2 * c) ^ (((m >> 2) & 3) << 4)))
                = f2bf(dqk[r] + bias_qk[r]);
        }
        #pragma unroll
        for (int ot = 0; ot < 2; ++ot) {
            f32x16 dv = zf;
            #pragma unroll
            for (int cc = 0; cc < 4; ++cc)
                dv = __builtin_amdgcn_mfma_f32_32x32x16_bf16(wvf[ot][cc].s, xw[cc].s, dv, 0, 0, 0);
            #pragma unroll
            for (int r = 0; r < 16; ++r) {
                const int ch = ot * 32 + (r & 3) + 8 * (r >> 2) + 4 * h;
                *(unsigned short*)(smem + VS_OFF + ((ch * 1152 + 2 * m) ^ ((ch & 7) << 4)))
                    = f2bf(dv[r] + bvv[ot][r]);
            }
        }
    }
    __syncthreads();

    const short8 qf0 = qfr[0].s, qf1 = qfr[1].s;
    f32x16 accA = zf, accB = zf, accC = zf, accD = zf;
    float ls0 = 0.f, ls1 = 0.f;
    const int chA = l32, chB = 32 + l32;
    const int swzA = (chA & 7) << 4, swzB = (chB & 7) << 4;

    #pragma unroll 1
    for (int mt = 0; mt < 18; ++mt) {
        const int m0 = mt * 32;
        const int mr = m0 + l32;
        const short8 kf = *(const short8*)(smem + KT_OFF + ((mr * 32 + 16 * h) ^ (((mr >> 2) & 3) << 4)));
        f32x16 s0 = __builtin_amdgcn_mfma_f32_32x32x16_bf16(kf, qf0, zf, 0, 0, 0);
        f32x16 s1 = __builtin_amdgcn_mfma_f32_32x32x16_bf16(kf, qf1, zf, 0, 0, 0);

        const short8 vA0 = *(const short8*)(smem + VS_OFF + ((chA * 1152 + 2 * (m0 + 8 * h)) ^ swzA));
        const short8 vA1 = *(const short8*)(smem + VS_OFF + ((chA * 1152 + 2 * (m0 + 16 + 8 * h)) ^ swzA));
        const short8 vB0 = *(const short8*)(smem + VS_OFF + ((chB * 1152 + 2 * (m0 + 8 * h)) ^ swzB));
        const short8 vB1 = *(const short8*)(smem + VS_OFF + ((chB * 1152 + 2 * (m0 + 16 + 8 * h)) ^ swzB));

        #pragma unroll
        for (int r = 0; r < 16; ++r) s0[r] = __expf(s0[r]);
        #pragma unroll
        for (int r = 0; r < 16; ++r) s1[r] = __expf(s1[r]);
        ls0 += ((s0[0]+s0[1])+(s0[2]+s0[3])) + ((s0[4]+s0[5])+(s0[6]+s0[7]))
             + ((s0[8]+s0[9])+(s0[10]+s0[11])) + ((s0[12]+s0[13])+(s0[14]+s0[15]));
        ls1 += ((s1[0]+s1[1])+(s1[2]+s1[3])) + ((s1[4]+s1[5])+(s1[6]+s1[7]))
             + ((s1[8]+s1[9])+(s1[10]+s1[11])) + ((s1[12]+s1[13])+(s1[14]+s1[15]));

        FragW pf00, pf01, pf10, pf11;
        {
            unsigned A0 = pk2(s0[0], s0[1]), B0 = pk2(s0[2], s0[3]);
            unsigned C0 = pk2(s0[4], s0[5]), D0 = pk2(s0[6], s0[7]);
            plswap(A0, C0); plswap(B0, D0);
            pf00.u[0] = A0; pf00.u[1] = B0; pf00.u[2] = C0; pf00.u[3] = D0;
            unsigned E0 = pk2(s0[8], s0[9]),  F0 = pk2(s0[10], s0[11]);
            unsigned G0 = pk2(s0[12], s0[13]), H0 = pk2(s0[14], s0[15]);
            plswap(E0, G0); plswap(F0, H0);
            pf01.u[0] = E0; pf01.u[1] = F0; pf01.u[2] = G0; pf01.u[3] = H0;
            unsigned A1 = pk2(s1[0], s1[1]), B1 = pk2(s1[2], s1[3]);
            unsigned C1 = pk2(s1[4], s1[5]), D1 = pk2(s1[6], s1[7]);
            plswap(A1, C1); plswap(B1, D1);
            pf10.u[0] = A1; pf10.u[1] = B1; pf10.u[2] = C1; pf10.u[3] = D1;
            unsigned E1 = pk2(s1[8], s1[9]),  F1 = pk2(s1[10], s1[11]);
            unsigned G1 = pk2(s1[12], s1[13]), H1 = pk2(s1[14], s1[15]);
            plswap(E1, G1); plswap(F1, H1);
            pf11.u[0] = E1; pf11.u[1] = F1; pf11.u[2] = G1; pf11.u[3] = H1;
        }

        accA = __builtin_amdgcn_mfma_f32_32x32x16_bf16(vA0, pf00.s, accA, 0, 0, 0);
        accA = __builtin_amdgcn_mfma_f32_32x32x16_bf16(vA1, pf01.s, accA, 0, 0, 0);
        accB = __builtin_amdgcn_mfma_f32_32x32x16_bf16(vB0, pf00.s, accB, 0, 0, 0);
        accB = __builtin_amdgcn_mfma_f32_32x32x16_bf16(vB1, pf01.s, accB, 0, 0, 0);
        accC = __builtin_amdgcn_mfma_f32_32x32x16_bf16(vA0, pf10.s, accC, 0, 0, 0);
        accC = __builtin_amdgcn_mfma_f32_32x32x16_bf16(vA1, pf11.s, accC, 0, 0, 0);
        accD = __builtin_amdgcn_mfma_f32_32x32x16_bf16(vB0, pf10.s, accD, 0, 0, 0);
        accD = __builtin_amdgcn_mfma_f32_32x32x16_bf16(vB1, pf11.s, accD, 0, 0, 0);
    }

    ls0 += __shfl_xor(ls0, 32);
    ls1 += __shfl_xor(ls1, 32);
    const float g2 = gamma[0];
    const float inv0 = 1.f / ls0, inv1 = 1.f / ls1;

    // final = g2 * att + out1 (residual via identity MFMA), in-place per tile
    #pragma unroll
    for (int t = 0; t < 2; ++t) {
        char* rec = xh + prec[t];
        FragW x0, x1, x2, x3;
        x0.s = *(const short8*)(rec + 0 * 32 + 16 * h);
        x1.s = *(const short8*)(rec + 1 * 32 + 16 * h);
        x2.s = *(const short8*)(rec + 2 * 32 + 16 * h);
        x3.s = *(const short8*)(rec + 3 * 32 + 16 * h);
        f32x16 r01 = __builtin_amdgcn_mfma_f32_32x32x16_bf16(Ihi.s, x1.s, zf, 0, 0, 0);
        r01 = __builtin_amdgcn_mfma_f32_32x32x16_bf16(Ilo.s, x0.s, r01, 0, 0, 0);
        f32x16 r23 = __builtin_amdgcn_mfma_f32_32x32x16_bf16(Ihi.s, x3.s, zf, 0, 0, 0);
        r23 = __builtin_amdgcn_mfma_f32_32x32x16_bf16(Ilo.s, x2.s, r23, 0, 0, 0);

        const f32x16 aclo = t ? accC : accA;
        const f32x16 achi = t ? accD : accB;
        const float inv = t ? inv1 : inv0;

        #pragma unroll
        for (int q = 0; q < 4; ++q) {
            const float a0 = fmaf(g2, aclo[4*q+0] * inv, r01[4*q+0]);
            const float a1 = fmaf(g2, aclo[4*q+1] * inv, r01[4*q+1]);
            const float a2 = fmaf(g2, aclo[4*q+2] * inv, r01[4*q+2]);
            const float a3 = fmaf(g2, aclo[4*q+3] * inv, r01[4*q+3]);
            uint2 wA; wA.x = pk2(a0, a1); wA.y = pk2(a2, a3);
            *(uint2*)(rec + 16 * q + 8 * h) = wA;
            const float b0 = fmaf(g2, achi[4*q+0] * inv, r23[4*q+0]);
            const float b1 = fmaf(g2, achi[4*q+1] * inv, r23[4*q+1]);
            const float b2 = fmaf(g2, achi[4*q+2] * inv, r23[4*q+2]);
            const float b3 = fmaf(g2, achi[4*q+3] * inv, r23[4*q+3]);
            uint2 wB; wB.x = pk2(b0, b1); wB.y = pk2(b2, b3);
            *(uint2*)(rec + 64 + 16 * q + 8 * h) = wB;
        }
    }
}

// ---------------- K4: NHWC bf16 records -> out NCHW f32 (write-only) ---------
__global__ __launch_bounds__(256) void to_nchw_kernel(
    float* __restrict__ out, const char* __restrict__ xh)
{
    __shared__ char smem[24576];

    const int bid = blockIdx.x;
    const int b = bid / 192, y = bid % 192;
    const int tid = threadIdx.x;

    const char* src = xh + ((size_t)b * HW + (size_t)y * 192) * 128;
    #pragma unroll
    for (int k = 0; k < 6; ++k) {
        const int off = k * 4096 + tid * 16;
        const int xq = off >> 7;
        const int gq = (off >> 4) & 7;
        const short8 v = *(const short8*)(src + off);
        *(short8*)(smem + (xq << 7) + (((gq ^ (xq & 7)) << 4))) = v;
    }
    __syncthreads();

    const int w = tid >> 6, lane = tid & 63;
    const size_t rowbase = (size_t)b * 64 * HW + (size_t)y * 192;

    #pragma unroll
    for (int it = 0; it < 24; ++it) {
        const int tt = it * 4 + w;
        const int chp = tt & 31;
        const int xb = tt >> 5;
        const int xx = xb * 64 + lane;
        const int byte_in_rec = chp * 4;
        const int gq = byte_in_rec >> 4;
        const unsigned v = *(const unsigned*)(smem + (xx << 7)
                            + ((gq ^ (xx & 7)) << 4) + (byte_in_rec & 15));
        const size_t o0 = rowbase + (size_t)(2 * chp) * HW + xx;
        out[o0]      = BLO(v);
        out[o0 + HW] = BHI(v);
    }
}

extern "C" void kernel_launch(void* const* d_in, const int* in_sizes, int n_in,
                              void* d_out, int out_size, void* d_ws, size_t ws_size,
                              hipStream_t stream)
{
    const float* x   = (const float*)d_in[0];
    const float* wq1 = (const float*)d_in[1];
    const float* bq1 = (const float*)d_in[2];
    const float* wk1 = (const float*)d_in[3];
    const float* bk1 = (const float*)d_in[4];
    const float* wv1 = (const float*)d_in[5];
    const float* bv1 = (const float*)d_in[6];
    const float* wq2 = (const float*)d_in[7];
    const float* bq2 = (const float*)d_in[8];
    const float* wk2 = (const float*)d_in[9];
    const float* bk2 = (const float*)d_in[10];
    const float* wv2 = (const float*)d_in[11];
    const float* bv2 = (const float*)d_in[12];
    const float* g1  = (const float*)d_in[13];
    const float* g2  = (const float*)d_in[14];
    float* out = (float*)d_out;
    char* xh = (char*)d_ws;

    to_nhwc_kernel<<<dim3(1536), dim3(256), 0, stream>>>(x, xh);

    attn1n_kernel<<<dim3(1152), dim3(256), 0, stream>>>(
        xh, wq1, bq1, wk1, bk1, wv1, bv1, g1);

    attn2n_kernel<<<dim3(512), dim3(576), 0, stream>>>(
        xh, wq2, bq2, wk2, bk2, wv2, bv2, g2);

    to_nchw_kernel<<<dim3(1536), dim3(256), 0, stream>>>(out, xh);
}